// Round 1
// baseline (1744.352 us; speedup 1.0000x reference)
//
#include <hip/hip_runtime.h>
#include <hip/hip_bf16.h>

#define N_FP 10000
#define EMB 64
#define L_CONV 5
#define CC 256
#define HID 512
#define N_NODES 40000
#define N_EDGES 640000
#define N_GRAPHS 128

// ---------------- CSR build ----------------
__global__ void zero_ints(int* __restrict__ p, int n) {
  int i = blockIdx.x * blockDim.x + threadIdx.x;
  if (i < n) p[i] = 0;
}

__global__ void count_deg(const int* __restrict__ dst, int* __restrict__ deg) {
  int e = blockIdx.x * blockDim.x + threadIdx.x;
  if (e < N_EDGES) atomicAdd(&deg[dst[e]], 1);
}

// single-block scan: 256 threads x 160 elems = 40960 >= 40001
__global__ void scan_deg(const int* __restrict__ deg, int* __restrict__ offs,
                         int* __restrict__ cursor) {
  __shared__ int tot[256];
  const int SEG = 160;
  int t = threadIdx.x;
  int base = t * SEG;
  int s = 0;
  for (int i = 0; i < SEG; ++i) {
    int idx = base + i;
    if (idx < N_NODES) s += deg[idx];
  }
  tot[t] = s;
  __syncthreads();
  for (int off = 1; off < 256; off <<= 1) {
    int v = (t >= off) ? tot[t - off] : 0;
    __syncthreads();
    tot[t] += v;
    __syncthreads();
  }
  int carry = (t == 0) ? 0 : tot[t - 1];
  s = carry;
  for (int i = 0; i < SEG; ++i) {
    int idx = base + i;
    if (idx < N_NODES) {
      offs[idx] = s;
      cursor[idx] = s;
      s += deg[idx];
    }
  }
  if (t == 255) offs[N_NODES] = tot[255];
}

__global__ void scatter_edges(const int* __restrict__ src, const int* __restrict__ dst,
                              int* __restrict__ cursor, int* __restrict__ csr) {
  int e = blockIdx.x * blockDim.x + threadIdx.x;
  if (e < N_EDGES) {
    int d = dst[e];
    int slot = atomicAdd(&cursor[d], 1);
    csr[slot] = src[e];
  }
}

// ---------------- embedding gather ----------------
__global__ void embed_gather(const int* __restrict__ x_idx, const float* __restrict__ emb,
                             float* __restrict__ x0) {
  int i = blockIdx.x * 256 + threadIdx.x;
  int n = i >> 6;
  int c = i & 63;
  x0[i] = emb[(size_t)x_idx[n] * EMB + c];
}

// ---------------- neighbor aggregation (segment_sum over in-edges) ----------------
template<int CIN>
__global__ void aggregate(const float* __restrict__ x, const int* __restrict__ offs,
                          const int* __restrict__ csr, float* __restrict__ agg) {
  int n = blockIdx.x;
  int c = threadIdx.x;
  int s = offs[n], e = offs[n + 1];
  float acc = 0.f;
  for (int j = s; j < e; ++j) {
    int sv = csr[j];
    acc += x[(size_t)sv * CIN + c];
  }
  agg[(size_t)n * CIN + c] = acc;
}

// ---------------- fused dual-A GEMM: out = relu(A1@W1 + A2@W2 + b) ----------------
#define BM 64
#define BN 128
#define BK 32

template<bool RELU>
__global__ __launch_bounds__(256)
void gemm_dualA(const float* __restrict__ A1, const float* __restrict__ A2,
                const float* __restrict__ W1, const float* __restrict__ W2,
                const float* __restrict__ bias, float* __restrict__ out,
                int M, int K1, int N) {
  __shared__ __align__(16) float As[BK][BM + 4];
  __shared__ __align__(16) float Ws[BK][BN];
  const int t = threadIdx.x;
  const int row0 = blockIdx.x * BM;
  const int col0 = blockIdx.y * BN;
  const int tx = t & 15;   // 16 col-groups x 8 cols
  const int ty = t >> 4;   // 16 row-groups x 4 rows
  float acc[4][8];
#pragma unroll
  for (int i = 0; i < 4; ++i)
#pragma unroll
    for (int j = 0; j < 8; ++j) acc[i][j] = 0.f;

  const int Ktot = 2 * K1;
  for (int k0 = 0; k0 < Ktot; k0 += BK) {
    const float* __restrict__ A = (k0 < K1) ? A1 : A2;
    const float* __restrict__ W = (k0 < K1) ? W1 : W2;
    const int kb = (k0 < K1) ? k0 : (k0 - K1);
    // A tile: 64 rows x 32 k, scalar coalesced loads
#pragma unroll
    for (int i = 0; i < 8; ++i) {
      int idx = t + i * 256;
      int m = idx >> 5;
      int k = idx & 31;
      As[k][m] = A[(size_t)(row0 + m) * K1 + kb + k];
    }
    // W tile: 32 k x 128 n, float4 coalesced loads
#pragma unroll
    for (int i = 0; i < 4; ++i) {
      int idx = t + i * 256;
      int k = idx >> 5;
      int nq = idx & 31;
      float4 v = *(const float4*)(W + (size_t)(kb + k) * N + col0 + nq * 4);
      *(float4*)&Ws[k][nq * 4] = v;
    }
    __syncthreads();
#pragma unroll
    for (int kk = 0; kk < BK; ++kk) {
      float4 av = *(const float4*)&As[kk][ty * 4];
      float4 b0 = *(const float4*)&Ws[kk][tx * 8];
      float4 b1 = *(const float4*)&Ws[kk][tx * 8 + 4];
      float a[4] = {av.x, av.y, av.z, av.w};
      float b[8] = {b0.x, b0.y, b0.z, b0.w, b1.x, b1.y, b1.z, b1.w};
#pragma unroll
      for (int i = 0; i < 4; ++i)
#pragma unroll
        for (int j = 0; j < 8; ++j)
          acc[i][j] = fmaf(a[i], b[j], acc[i][j]);
    }
    __syncthreads();
  }
#pragma unroll
  for (int i = 0; i < 4; ++i) {
    int m = row0 + ty * 4 + i;
#pragma unroll
    for (int j = 0; j < 8; ++j) {
      int n = col0 + tx * 8 + j;
      float v = acc[i][j] + bias[n];
      if (RELU) v = fmaxf(v, 0.f);
      out[(size_t)m * N + n] = v;
    }
  }
}

// ---------------- global_add_pool (batch is sorted) ----------------
__global__ void pool_sum(const float* __restrict__ x, const int* __restrict__ batch,
                         float* __restrict__ g) {
  int gr = blockIdx.x;
  int c = blockIdx.y * 64 + threadIdx.x;
  int lo = 0, hi = N_NODES;
  while (lo < hi) { int mid = (lo + hi) >> 1; if (batch[mid] < gr) lo = mid + 1; else hi = mid; }
  int s = lo;
  hi = N_NODES;
  while (lo < hi) { int mid = (lo + hi) >> 1; if (batch[mid] <= gr) lo = mid + 1; else hi = mid; }
  int e = lo;
  float acc = 0.f;
  for (int i = s; i < e; ++i) acc += x[(size_t)i * CC + c];
  g[(size_t)gr * CC + c] = acc;
}

// ---------------- small MLP layers ----------------
template<int K, bool RELU>
__global__ void small_linear(const float* __restrict__ A, const float* __restrict__ W,
                             const float* __restrict__ bias, float* __restrict__ out, int N) {
  int g = blockIdx.x;
  int n = blockIdx.y * 64 + threadIdx.x;
  const float* a = A + (size_t)g * K;
  float acc = bias[n];
  for (int k = 0; k < K; ++k) acc = fmaf(a[k], W[(size_t)k * N + n], acc);
  if (RELU) acc = fmaxf(acc, 0.f);
  out[(size_t)g * N + n] = acc;
}

__global__ void out_layer(const float* __restrict__ h, const float* __restrict__ w,
                          const float* __restrict__ b, float* __restrict__ out) {
  int g = blockIdx.x;
  int t = threadIdx.x; // 64
  float acc = 0.f;
  for (int k = t; k < HID; k += 64) acc = fmaf(h[(size_t)g * HID + k], w[k], acc);
  for (int off = 32; off > 0; off >>= 1) acc += __shfl_down(acc, off);
  if (t == 0) out[g] = acc + b[0];
}

extern "C" void kernel_launch(void* const* d_in, const int* in_sizes, int n_in,
                              void* d_out, int out_size, void* d_ws, size_t ws_size,
                              hipStream_t stream) {
  const int* x_idx = (const int*)d_in[0];
  const int* edge_index = (const int*)d_in[1];
  const int* batch = (const int*)d_in[2];
  const float* embed = (const float*)d_in[3];
  const float* w_rel0 = (const float*)d_in[4];
  const float* b_rel0 = (const float*)d_in[5];
  const float* w_root0 = (const float*)d_in[6];
  const float* w_rel = (const float*)d_in[7];
  const float* b_rel = (const float*)d_in[8];
  const float* w_root = (const float*)d_in[9];
  const float* w_lin0 = (const float*)d_in[10];
  const float* b_lin0 = (const float*)d_in[11];
  const float* w_lin = (const float*)d_in[12];
  const float* b_lin = (const float*)d_in[13];
  const float* w_out = (const float*)d_in[14];
  const float* b_out = (const float*)d_in[15];
  float* out = (float*)d_out;

  const int* src = edge_index;
  const int* dst = edge_index + N_EDGES;

  char* ws = (char*)d_ws;
  size_t off = 0;
  auto alloc = [&](size_t bytes) -> void* {
    void* p = ws + off;
    off = (off + bytes + 255) & ~(size_t)255;
    return p;
  };
  int* deg    = (int*)alloc((size_t)N_NODES * 4);
  int* cursor = (int*)alloc((size_t)N_NODES * 4);
  int* offs   = (int*)alloc((size_t)(N_NODES + 1) * 4);
  int* csr    = (int*)alloc((size_t)N_EDGES * 4);
  float* xA   = (float*)alloc((size_t)N_NODES * CC * 4);
  float* xB   = (float*)alloc((size_t)N_NODES * CC * 4);
  float* agg  = (float*)alloc((size_t)N_NODES * CC * 4);
  float* gb   = (float*)alloc((size_t)N_GRAPHS * CC * 4);
  float* h1   = (float*)alloc((size_t)N_GRAPHS * HID * 4);
  float* h2   = (float*)alloc((size_t)N_GRAPHS * HID * 4);

  // CSR build (per call; deterministic up to fp-neutral edge ordering)
  zero_ints<<<(N_NODES + 255) / 256, 256, 0, stream>>>(deg, N_NODES);
  count_deg<<<N_EDGES / 256, 256, 0, stream>>>(dst, deg);
  scan_deg<<<1, 256, 0, stream>>>(deg, offs, cursor);
  scatter_edges<<<N_EDGES / 256, 256, 0, stream>>>(src, dst, cursor, csr);

  // x0 = embed[x_idx]  [N, 64]
  embed_gather<<<(N_NODES * EMB) / 256, 256, 0, stream>>>(x_idx, embed, xA);

  dim3 gemm_grid(N_NODES / BM, CC / BN);

  // layer 0: EMB -> CC
  aggregate<EMB><<<N_NODES, EMB, 0, stream>>>(xA, offs, csr, agg);
  gemm_dualA<true><<<gemm_grid, 256, 0, stream>>>(agg, xA, w_rel0, w_root0, b_rel0,
                                                  xB, N_NODES, EMB, CC);

  // layers 1..5: CC -> CC
  float* cur = xB;
  float* nxt = xA;
  for (int l = 0; l < L_CONV; ++l) {
    aggregate<CC><<<N_NODES, CC, 0, stream>>>(cur, offs, csr, agg);
    gemm_dualA<true><<<gemm_grid, 256, 0, stream>>>(agg, cur,
        w_rel + (size_t)l * CC * CC, w_root + (size_t)l * CC * CC,
        b_rel + (size_t)l * CC, nxt, N_NODES, CC, CC);
    float* tmp = cur; cur = nxt; nxt = tmp;
  }

  // pooling + MLP
  pool_sum<<<dim3(N_GRAPHS, CC / 64), 64, 0, stream>>>(cur, batch, gb);
  small_linear<CC, true><<<dim3(N_GRAPHS, HID / 64), 64, 0, stream>>>(gb, w_lin0, b_lin0, h1, HID);
  small_linear<HID, true><<<dim3(N_GRAPHS, HID / 64), 64, 0, stream>>>(h1, w_lin, b_lin, h2, HID);
  small_linear<HID, true><<<dim3(N_GRAPHS, HID / 64), 64, 0, stream>>>(h2, w_lin + HID * HID, b_lin + HID, h1, HID);
  out_layer<<<N_GRAPHS, 64, 0, stream>>>(h1, w_out, b_out, out);
}

// Round 2
// 1203.660 us; speedup vs baseline: 1.4492x; 1.4492x over previous
//
#include <hip/hip_runtime.h>
#include <hip/hip_bf16.h>

#define N_FP 10000
#define EMB 64
#define L_CONV 5
#define CC 256
#define HID 512
#define N_NODES 40000
#define N_EDGES 640000
#define N_GRAPHS 128
#define MP 40064  // N_NODES padded to multiple of 128

typedef __attribute__((ext_vector_type(8))) short short8;
typedef __attribute__((ext_vector_type(4))) float f32x4;

// ---------- bf16 split helpers ----------
__device__ inline unsigned short f2bf(float x) {
  __hip_bfloat16 b = __float2bfloat16(x);
  return *reinterpret_cast<unsigned short*>(&b);
}
__device__ inline float bf2f(unsigned short u) {
  unsigned int v = (unsigned int)u << 16;
  return __uint_as_float(v);
}
__device__ inline unsigned int pack_split(float x) {
  unsigned short hb = f2bf(x);
  float h = bf2f(hb);
  unsigned short lb = f2bf(x - h);
  return ((unsigned int)hb << 16) | lb;
}
__device__ inline float unpack(unsigned int u) {
  return __uint_as_float(u & 0xffff0000u) + bf2f((unsigned short)(u & 0xffffu));
}

// ---------------- CSR build ----------------
__global__ void zero_ints(int* __restrict__ p, int n) {
  int i = blockIdx.x * blockDim.x + threadIdx.x;
  if (i < n) p[i] = 0;
}

__global__ void count_deg(const int* __restrict__ dst, int* __restrict__ deg) {
  int e = blockIdx.x * blockDim.x + threadIdx.x;
  if (e < N_EDGES) atomicAdd(&deg[dst[e]], 1);
}

__global__ void scan_deg(const int* __restrict__ deg, int* __restrict__ offs,
                         int* __restrict__ cursor) {
  __shared__ int tot[256];
  const int SEG = 160;
  int t = threadIdx.x;
  int base = t * SEG;
  int s = 0;
  for (int i = 0; i < SEG; ++i) {
    int idx = base + i;
    if (idx < N_NODES) s += deg[idx];
  }
  tot[t] = s;
  __syncthreads();
  for (int off = 1; off < 256; off <<= 1) {
    int v = (t >= off) ? tot[t - off] : 0;
    __syncthreads();
    tot[t] += v;
    __syncthreads();
  }
  int carry = (t == 0) ? 0 : tot[t - 1];
  s = carry;
  for (int i = 0; i < SEG; ++i) {
    int idx = base + i;
    if (idx < N_NODES) {
      offs[idx] = s;
      cursor[idx] = s;
      s += deg[idx];
    }
  }
  if (t == 255) offs[N_NODES] = tot[255];
}

__global__ void scatter_edges(const int* __restrict__ src, const int* __restrict__ dst,
                              int* __restrict__ cursor, int* __restrict__ csr) {
  int e = blockIdx.x * blockDim.x + threadIdx.x;
  if (e < N_EDGES) {
    int d = dst[e];
    int slot = atomicAdd(&cursor[d], 1);
    csr[slot] = src[e];
  }
}

// ---------------- weight transpose + split: W[K][N] -> hi/lo[N][K] ----------------
__global__ void transpose_split(const float* __restrict__ W, unsigned short* __restrict__ hi,
                                unsigned short* __restrict__ lo, int K, int N) {
  int i = blockIdx.x * 256 + threadIdx.x;
  if (i >= K * N) return;
  int k = i / N, n = i % N;
  float x = W[i];
  unsigned short hb = f2bf(x);
  float h = bf2f(hb);
  unsigned short lb = f2bf(x - h);
  hi[(size_t)n * K + k] = hb;
  lo[(size_t)n * K + k] = lb;
}

// ---------------- embedding gather (packed) ----------------
__global__ void embed_gather_pack(const int* __restrict__ x_idx, const float* __restrict__ emb,
                                  unsigned int* __restrict__ x0p) {
  int i = blockIdx.x * 256 + threadIdx.x;
  int n = i >> 6;
  int c = i & 63;
  x0p[i] = pack_split(emb[(size_t)x_idx[n] * EMB + c]);
}

// ---------------- aggregation: wave per node, packed hi/lo ----------------
template<int CIN>
__global__ void aggregate_pack(const unsigned int* __restrict__ xp, const int* __restrict__ offs,
                               const int* __restrict__ csr, unsigned int* __restrict__ aggp) {
  int wid = (blockIdx.x * blockDim.x + threadIdx.x) >> 6;
  int lane = threadIdx.x & 63;
  if (wid >= N_NODES) return;
  int s = offs[wid], e = offs[wid + 1];
  if (CIN == 256) {
    float a0 = 0.f, a1 = 0.f, a2 = 0.f, a3 = 0.f;
    for (int j = s; j < e; ++j) {
      int sv = csr[j];
      uint4 v = *(const uint4*)(xp + (size_t)sv * 256 + lane * 4);
      a0 += unpack(v.x); a1 += unpack(v.y); a2 += unpack(v.z); a3 += unpack(v.w);
    }
    uint4 o;
    o.x = pack_split(a0); o.y = pack_split(a1); o.z = pack_split(a2); o.w = pack_split(a3);
    *(uint4*)(aggp + (size_t)wid * 256 + lane * 4) = o;
  } else {
    float a = 0.f;
    for (int j = s; j < e; ++j) a += unpack(xp[(size_t)csr[j] * 64 + lane]);
    aggp[(size_t)wid * 64 + lane] = pack_split(a);
  }
}

// ---------------- MFMA split-bf16 dual GEMM ----------------
// out = relu(A1@W1 + A2@W2 + bias); A packed u32 hi/lo [MP][K1];
// W given transposed+split: [256 n][K1 k] bf16 hi/lo.
// 3-pass split per product: Ah*Wh + Al*Wh + Ah*Wl (drop Al*Wl ~1.6e-5).
template<int K1>
__global__ __launch_bounds__(256)
void gemm_conv(const unsigned int* __restrict__ A1, const unsigned int* __restrict__ A2,
               const unsigned short* __restrict__ W1h, const unsigned short* __restrict__ W1l,
               const unsigned short* __restrict__ W2h, const unsigned short* __restrict__ W2l,
               const float* __restrict__ bias, unsigned int* __restrict__ outp) {
  __shared__ __align__(16) unsigned short As_hi[128 * 40];
  __shared__ __align__(16) unsigned short As_lo[128 * 40];
  __shared__ __align__(16) unsigned short Bs_hi[128 * 40];
  __shared__ __align__(16) unsigned short Bs_lo[128 * 40];

  const int t = threadIdx.x;
  const int row0 = blockIdx.x * 128;
  const int col0 = blockIdx.y * 128;
  const int lane = t & 63;
  const int wave = t >> 6;
  const int wm = wave >> 1;   // 2x2 wave grid; each wave does 64x64
  const int wn = wave & 1;
  const int fr = lane & 15;   // fragment row / col
  const int fg = lane >> 4;   // k-group

  f32x4 acc[4][4];
#pragma unroll
  for (int i = 0; i < 4; ++i)
#pragma unroll
    for (int j = 0; j < 4; ++j) acc[i][j] = (f32x4)(0.f);

  for (int srcp = 0; srcp < 2; ++srcp) {
    const unsigned int* __restrict__ Asrc = srcp ? A2 : A1;
    const unsigned short* __restrict__ Bh = srcp ? W2h : W1h;
    const unsigned short* __restrict__ Bl = srcp ? W2l : W1l;
    for (int ks = 0; ks < K1 / 32; ++ks) {
      const int kb = ks * 32;
      // stage A tile: 128 rows x 32 k (packed u32) -> unpack hi/lo
#pragma unroll
      for (int i = 0; i < 4; ++i) {
        int idx = t + i * 256;
        int r = idx >> 3;
        int q = idx & 7;
        uint4 v = *(const uint4*)(Asrc + (size_t)(row0 + r) * K1 + kb + q * 4);
        ushort4 h, l;
        h.x = (unsigned short)(v.x >> 16); l.x = (unsigned short)(v.x & 0xffff);
        h.y = (unsigned short)(v.y >> 16); l.y = (unsigned short)(v.y & 0xffff);
        h.z = (unsigned short)(v.z >> 16); l.z = (unsigned short)(v.z & 0xffff);
        h.w = (unsigned short)(v.w >> 16); l.w = (unsigned short)(v.w & 0xffff);
        *(ushort4*)(As_hi + r * 40 + q * 4) = h;
        *(ushort4*)(As_lo + r * 40 + q * 4) = l;
      }
      // stage B tile: 128 n-rows x 32 k (bf16), already transposed+split
#pragma unroll
      for (int i = 0; i < 2; ++i) {
        int idx = t + i * 256;
        int r = idx >> 2;
        int q = idx & 3;
        uint4 vh = *(const uint4*)(Bh + (size_t)(col0 + r) * K1 + kb + q * 8);
        *(uint4*)(Bs_hi + r * 40 + q * 8) = vh;
        uint4 vl = *(const uint4*)(Bl + (size_t)(col0 + r) * K1 + kb + q * 8);
        *(uint4*)(Bs_lo + r * 40 + q * 8) = vl;
      }
      __syncthreads();

      short8 ah[4], al[4];
#pragma unroll
      for (int mi = 0; mi < 4; ++mi) {
        int r = wm * 64 + mi * 16 + fr;
        ah[mi] = *(const short8*)(As_hi + r * 40 + fg * 8);
        al[mi] = *(const short8*)(As_lo + r * 40 + fg * 8);
      }
#pragma unroll
      for (int ni = 0; ni < 4; ++ni) {
        int rn = wn * 64 + ni * 16 + fr;
        short8 bh = *(const short8*)(Bs_hi + rn * 40 + fg * 8);
        short8 bl = *(const short8*)(Bs_lo + rn * 40 + fg * 8);
#pragma unroll
        for (int mi = 0; mi < 4; ++mi) {
          acc[mi][ni] = __builtin_amdgcn_mfma_f32_16x16x32_bf16(ah[mi], bh, acc[mi][ni], 0, 0, 0);
          acc[mi][ni] = __builtin_amdgcn_mfma_f32_16x16x32_bf16(al[mi], bh, acc[mi][ni], 0, 0, 0);
          acc[mi][ni] = __builtin_amdgcn_mfma_f32_16x16x32_bf16(ah[mi], bl, acc[mi][ni], 0, 0, 0);
        }
      }
      __syncthreads();
    }
  }

  // epilogue: bias + relu + split-pack + store
#pragma unroll
  for (int ni = 0; ni < 4; ++ni) {
    int col = col0 + wn * 64 + ni * 16 + fr;
    float b = bias[col];
#pragma unroll
    for (int mi = 0; mi < 4; ++mi) {
#pragma unroll
      for (int r = 0; r < 4; ++r) {
        int row = row0 + wm * 64 + mi * 16 + fg * 4 + r;
        float v = acc[mi][ni][r] + b;
        v = fmaxf(v, 0.f);
        outp[(size_t)row * 256 + col] = pack_split(v);
      }
    }
  }
}

// ---------------- global_add_pool (batch sorted), packed input ----------------
__global__ void pool_sum_pack(const unsigned int* __restrict__ xp, const int* __restrict__ batch,
                              float* __restrict__ g) {
  int gr = blockIdx.x;
  int lane = threadIdx.x; // 64
  int lo = 0, hi = N_NODES;
  while (lo < hi) { int mid = (lo + hi) >> 1; if (batch[mid] < gr) lo = mid + 1; else hi = mid; }
  int s = lo;
  hi = N_NODES;
  while (lo < hi) { int mid = (lo + hi) >> 1; if (batch[mid] <= gr) lo = mid + 1; else hi = mid; }
  int e = lo;
  float a0 = 0.f, a1 = 0.f, a2 = 0.f, a3 = 0.f;
  for (int i = s; i < e; ++i) {
    uint4 v = *(const uint4*)(xp + (size_t)i * 256 + lane * 4);
    a0 += unpack(v.x); a1 += unpack(v.y); a2 += unpack(v.z); a3 += unpack(v.w);
  }
  float4 o = make_float4(a0, a1, a2, a3);
  *(float4*)(g + (size_t)gr * 256 + lane * 4) = o;
}

// ---------------- small MLP layers (fp32) ----------------
template<int K, bool RELU>
__global__ void small_linear(const float* __restrict__ A, const float* __restrict__ W,
                             const float* __restrict__ bias, float* __restrict__ out, int N) {
  int g = blockIdx.x;
  int n = blockIdx.y * 64 + threadIdx.x;
  const float* a = A + (size_t)g * K;
  float acc = bias[n];
  for (int k = 0; k < K; ++k) acc = fmaf(a[k], W[(size_t)k * N + n], acc);
  if (RELU) acc = fmaxf(acc, 0.f);
  out[(size_t)g * N + n] = acc;
}

__global__ void out_layer(const float* __restrict__ h, const float* __restrict__ w,
                          const float* __restrict__ b, float* __restrict__ out) {
  int g = blockIdx.x;
  int t = threadIdx.x; // 64
  float acc = 0.f;
  for (int k = t; k < HID; k += 64) acc = fmaf(h[(size_t)g * HID + k], w[k], acc);
  for (int off = 32; off > 0; off >>= 1) acc += __shfl_down(acc, off);
  if (t == 0) out[g] = acc + b[0];
}

extern "C" void kernel_launch(void* const* d_in, const int* in_sizes, int n_in,
                              void* d_out, int out_size, void* d_ws, size_t ws_size,
                              hipStream_t stream) {
  const int* x_idx = (const int*)d_in[0];
  const int* edge_index = (const int*)d_in[1];
  const int* batch = (const int*)d_in[2];
  const float* embed = (const float*)d_in[3];
  const float* w_rel0 = (const float*)d_in[4];
  const float* b_rel0 = (const float*)d_in[5];
  const float* w_root0 = (const float*)d_in[6];
  const float* w_rel = (const float*)d_in[7];
  const float* b_rel = (const float*)d_in[8];
  const float* w_root = (const float*)d_in[9];
  const float* w_lin0 = (const float*)d_in[10];
  const float* b_lin0 = (const float*)d_in[11];
  const float* w_lin = (const float*)d_in[12];
  const float* b_lin = (const float*)d_in[13];
  const float* w_out = (const float*)d_in[14];
  const float* b_out = (const float*)d_in[15];
  float* out = (float*)d_out;

  const int* src = edge_index;
  const int* dst = edge_index + N_EDGES;

  char* ws = (char*)d_ws;
  size_t off = 0;
  auto alloc = [&](size_t bytes) -> void* {
    void* p = ws + off;
    off = (off + bytes + 255) & ~(size_t)255;
    return p;
  };
  int* deg    = (int*)alloc((size_t)N_NODES * 4);
  int* cursor = (int*)alloc((size_t)N_NODES * 4);
  int* offs   = (int*)alloc((size_t)(N_NODES + 1) * 4);
  int* csr    = (int*)alloc((size_t)N_EDGES * 4);
  unsigned int* x0p  = (unsigned int*)alloc((size_t)MP * EMB * 4);
  unsigned int* aggp = (unsigned int*)alloc((size_t)MP * CC * 4);
  unsigned int* xA   = (unsigned int*)alloc((size_t)MP * CC * 4);
  unsigned int* xB   = (unsigned int*)alloc((size_t)MP * CC * 4);
  unsigned short* w0rel_h  = (unsigned short*)alloc((size_t)CC * EMB * 2);
  unsigned short* w0rel_l  = (unsigned short*)alloc((size_t)CC * EMB * 2);
  unsigned short* w0root_h = (unsigned short*)alloc((size_t)CC * EMB * 2);
  unsigned short* w0root_l = (unsigned short*)alloc((size_t)CC * EMB * 2);
  unsigned short* wrel_h  = (unsigned short*)alloc((size_t)L_CONV * CC * CC * 2);
  unsigned short* wrel_l  = (unsigned short*)alloc((size_t)L_CONV * CC * CC * 2);
  unsigned short* wroot_h = (unsigned short*)alloc((size_t)L_CONV * CC * CC * 2);
  unsigned short* wroot_l = (unsigned short*)alloc((size_t)L_CONV * CC * CC * 2);
  float* gb   = (float*)alloc((size_t)N_GRAPHS * CC * 4);
  float* h1   = (float*)alloc((size_t)N_GRAPHS * HID * 4);
  float* h2   = (float*)alloc((size_t)N_GRAPHS * HID * 4);

  // CSR build
  zero_ints<<<(N_NODES + 255) / 256, 256, 0, stream>>>(deg, N_NODES);
  count_deg<<<N_EDGES / 256, 256, 0, stream>>>(dst, deg);
  scan_deg<<<1, 256, 0, stream>>>(deg, offs, cursor);
  scatter_edges<<<N_EDGES / 256, 256, 0, stream>>>(src, dst, cursor, csr);

  // weight prep: transpose + hi/lo split
  transpose_split<<<(EMB * CC + 255) / 256, 256, 0, stream>>>(w_rel0, w0rel_h, w0rel_l, EMB, CC);
  transpose_split<<<(EMB * CC + 255) / 256, 256, 0, stream>>>(w_root0, w0root_h, w0root_l, EMB, CC);
  for (int l = 0; l < L_CONV; ++l) {
    size_t o = (size_t)l * CC * CC;
    transpose_split<<<(CC * CC + 255) / 256, 256, 0, stream>>>(w_rel + o, wrel_h + o, wrel_l + o, CC, CC);
    transpose_split<<<(CC * CC + 255) / 256, 256, 0, stream>>>(w_root + o, wroot_h + o, wroot_l + o, CC, CC);
  }

  // x0 = embed[x_idx] packed
  embed_gather_pack<<<(N_NODES * EMB) / 256, 256, 0, stream>>>(x_idx, embed, x0p);

  dim3 gemm_grid(MP / 128, CC / 128);

  // layer 0: EMB -> CC
  aggregate_pack<EMB><<<(N_NODES + 3) / 4, 256, 0, stream>>>(x0p, offs, csr, aggp);
  gemm_conv<EMB><<<gemm_grid, 256, 0, stream>>>(aggp, x0p, w0rel_h, w0rel_l,
                                                w0root_h, w0root_l, b_rel0, xA);

  // layers 1..5
  unsigned int* cur = xA;
  unsigned int* nxt = xB;
  for (int l = 0; l < L_CONV; ++l) {
    size_t o = (size_t)l * CC * CC;
    aggregate_pack<CC><<<(N_NODES + 3) / 4, 256, 0, stream>>>(cur, offs, csr, aggp);
    gemm_conv<CC><<<gemm_grid, 256, 0, stream>>>(aggp, cur, wrel_h + o, wrel_l + o,
                                                 wroot_h + o, wroot_l + o,
                                                 b_rel + (size_t)l * CC, nxt);
    unsigned int* tmp = cur; cur = nxt; nxt = tmp;
  }

  // pooling + MLP
  pool_sum_pack<<<N_GRAPHS, 64, 0, stream>>>(cur, batch, gb);
  small_linear<CC, true><<<dim3(N_GRAPHS, HID / 64), 64, 0, stream>>>(gb, w_lin0, b_lin0, h1, HID);
  small_linear<HID, true><<<dim3(N_GRAPHS, HID / 64), 64, 0, stream>>>(h1, w_lin, b_lin, h2, HID);
  small_linear<HID, true><<<dim3(N_GRAPHS, HID / 64), 64, 0, stream>>>(h2, w_lin + HID * HID, b_lin + HID, h1, HID);
  out_layer<<<N_GRAPHS, 64, 0, stream>>>(h1, w_out, b_out, out);
}

// Round 3
// 1032.064 us; speedup vs baseline: 1.6902x; 1.1663x over previous
//
#include <hip/hip_runtime.h>
#include <hip/hip_bf16.h>

#define N_FP 10000
#define EMB 64
#define L_CONV 5
#define CC 256
#define HID 512
#define N_NODES 40000
#define N_EDGES 640000
#define N_GRAPHS 128
#define MP 40064           // N_NODES padded to multiple of 128
#define SCAN_BLOCKS 157    // ceil(40000/256)

typedef __attribute__((ext_vector_type(8))) short short8;
typedef __attribute__((ext_vector_type(4))) float f32x4;

// ---------- bf16 split helpers ----------
__device__ inline unsigned short f2bf(float x) {
  __hip_bfloat16 b = __float2bfloat16(x);
  return *reinterpret_cast<unsigned short*>(&b);
}
__device__ inline float bf2f(unsigned short u) {
  return __uint_as_float((unsigned int)u << 16);
}
__device__ inline void split2(float x, unsigned short* h, unsigned short* l) {
  unsigned short hb = f2bf(x);
  *h = hb;
  *l = f2bf(x - bf2f(hb));
}

// ---------------- CSR build ----------------
__global__ void zero_ints(int* __restrict__ p, int n) {
  int i = blockIdx.x * blockDim.x + threadIdx.x;
  if (i < n) p[i] = 0;
}

__global__ void count_deg(const int* __restrict__ dst, int* __restrict__ deg) {
  int e = blockIdx.x * blockDim.x + threadIdx.x;
  if (e < N_EDGES) atomicAdd(&deg[dst[e]], 1);
}

// parallel scan: per-block reduce -> tiny top scan -> per-block scan
__global__ void scan_partial(const int* __restrict__ deg, int* __restrict__ partial) {
  __shared__ int sm[256];
  int t = threadIdx.x;
  int idx = blockIdx.x * 256 + t;
  sm[t] = (idx < N_NODES) ? deg[idx] : 0;
  __syncthreads();
  for (int off = 128; off > 0; off >>= 1) {
    if (t < off) sm[t] += sm[t + off];
    __syncthreads();
  }
  if (t == 0) partial[blockIdx.x] = sm[0];
}

__global__ void scan_top(int* __restrict__ partial) {
  __shared__ int sm[256];
  int t = threadIdx.x;
  int own = (t < SCAN_BLOCKS) ? partial[t] : 0;
  sm[t] = own;
  __syncthreads();
  for (int off = 1; off < 256; off <<= 1) {
    int v = (t >= off) ? sm[t - off] : 0;
    __syncthreads();
    sm[t] += v;
    __syncthreads();
  }
  if (t < SCAN_BLOCKS) partial[t] = sm[t] - own;  // exclusive
}

__global__ void scan_final(const int* __restrict__ deg, const int* __restrict__ partial,
                           int* __restrict__ offs, int* __restrict__ cursor) {
  __shared__ int sm[256];
  int t = threadIdx.x;
  int idx = blockIdx.x * 256 + t;
  int own = (idx < N_NODES) ? deg[idx] : 0;
  sm[t] = own;
  __syncthreads();
  for (int off = 1; off < 256; off <<= 1) {
    int v = (t >= off) ? sm[t - off] : 0;
    __syncthreads();
    sm[t] += v;
    __syncthreads();
  }
  int excl = sm[t] - own + partial[blockIdx.x];
  if (idx < N_NODES) { offs[idx] = excl; cursor[idx] = excl; }
  if (idx == N_NODES - 1) offs[N_NODES] = excl + own;
}

__global__ void scatter_edges(const int* __restrict__ src, const int* __restrict__ dst,
                              int* __restrict__ cursor, int* __restrict__ csr) {
  int e = blockIdx.x * blockDim.x + threadIdx.x;
  if (e < N_EDGES) {
    int d = dst[e];
    int slot = atomicAdd(&cursor[d], 1);
    csr[slot] = src[e];
  }
}

// ---------------- weight transpose + split ----------------
__global__ void transpose_split(const float* __restrict__ W, unsigned short* __restrict__ hi,
                                unsigned short* __restrict__ lo, int K, int N) {
  int i = blockIdx.x * 256 + threadIdx.x;
  if (i >= K * N) return;
  int k = i / N, n = i % N;
  unsigned short hb, lb;
  split2(W[i], &hb, &lb);
  hi[(size_t)n * K + k] = hb;
  lo[(size_t)n * K + k] = lb;
}

// all L_CONV layers of one [L][CC][CC] weight stack in one launch
__global__ void transpose_split_all(const float* __restrict__ W, unsigned short* __restrict__ hi,
                                    unsigned short* __restrict__ lo) {
  int i = blockIdx.x * 256 + threadIdx.x;
  if (i >= L_CONV * CC * CC) return;
  int l = i >> 16;
  int rem = i & 65535;
  int k = rem >> 8, n = rem & 255;
  unsigned short hb, lb;
  split2(W[i], &hb, &lb);
  size_t o = ((size_t)l << 16) + n * CC + k;
  hi[o] = hb;
  lo[o] = lb;
}

// ---------------- embedding gather (hi/lo planes) ----------------
__global__ void embed_gather_split(const int* __restrict__ x_idx, const float* __restrict__ emb,
                                   unsigned short* __restrict__ xh, unsigned short* __restrict__ xl) {
  int i = blockIdx.x * 256 + threadIdx.x;
  int n = i >> 6;
  int c = i & 63;
  unsigned short hb, lb;
  split2(emb[(size_t)x_idx[n] * EMB + c], &hb, &lb);
  xh[i] = hb;
  xl[i] = lb;
}

// ---------------- aggregation: wave per node, bf16-hi gather ----------------
__global__ void aggregate_bf64(const unsigned short* __restrict__ xh, const int* __restrict__ offs,
                               const int* __restrict__ csr, unsigned short* __restrict__ aggh,
                               unsigned short* __restrict__ aggl) {
  int wid = (blockIdx.x * blockDim.x + threadIdx.x) >> 6;
  int lane = threadIdx.x & 63;
  if (wid >= N_NODES) return;
  int s = offs[wid], e = offs[wid + 1];
  float a = 0.f;
  for (int j = s; j < e; ++j) a += bf2f(xh[(size_t)csr[j] * 64 + lane]);
  unsigned short hb, lb;
  split2(a, &hb, &lb);
  aggh[(size_t)wid * 64 + lane] = hb;
  aggl[(size_t)wid * 64 + lane] = lb;
}

__global__ void aggregate_bf(const unsigned short* __restrict__ xh, const int* __restrict__ offs,
                             const int* __restrict__ csr, unsigned short* __restrict__ aggh,
                             unsigned short* __restrict__ aggl) {
  int wid = (blockIdx.x * blockDim.x + threadIdx.x) >> 6;
  int lane = threadIdx.x & 63;
  if (wid >= N_NODES) return;
  int s = offs[wid], e = offs[wid + 1];
  float a0 = 0.f, a1 = 0.f, a2 = 0.f, a3 = 0.f;
  for (int j = s; j < e; ++j) {
    int sv = csr[j];
    uint2 v = *(const uint2*)(xh + (size_t)sv * 256 + lane * 4);
    a0 += __uint_as_float(v.x << 16);
    a1 += __uint_as_float(v.x & 0xffff0000u);
    a2 += __uint_as_float(v.y << 16);
    a3 += __uint_as_float(v.y & 0xffff0000u);
  }
  ushort4 oh, ol;
  split2(a0, &oh.x, &ol.x);
  split2(a1, &oh.y, &ol.y);
  split2(a2, &oh.z, &ol.z);
  split2(a3, &oh.w, &ol.w);
  *(ushort4*)(aggh + (size_t)wid * 256 + lane * 4) = oh;
  *(ushort4*)(aggl + (size_t)wid * 256 + lane * 4) = ol;
}

// ---------------- MFMA split-bf16 dual GEMM (hi/lo planes) ----------------
// out = relu(A1@W1 + A2@W2 + bias); A as bf16 hi/lo planes [MP][K1];
// W transposed+split [256 n][K1 k] hi/lo. 3-pass: Ah*Wh + Al*Wh + Ah*Wl.
template<int K1>
__global__ __launch_bounds__(256)
void gemm_conv(const unsigned short* __restrict__ A1h, const unsigned short* __restrict__ A1l,
               const unsigned short* __restrict__ A2h, const unsigned short* __restrict__ A2l,
               const unsigned short* __restrict__ W1h, const unsigned short* __restrict__ W1l,
               const unsigned short* __restrict__ W2h, const unsigned short* __restrict__ W2l,
               const float* __restrict__ bias, unsigned short* __restrict__ outh,
               unsigned short* __restrict__ outl) {
  __shared__ __align__(16) unsigned short As_hi[128 * 40];
  __shared__ __align__(16) unsigned short As_lo[128 * 40];
  __shared__ __align__(16) unsigned short Bs_hi[128 * 40];
  __shared__ __align__(16) unsigned short Bs_lo[128 * 40];

  const int t = threadIdx.x;
  const int row0 = blockIdx.x * 128;
  const int col0 = blockIdx.y * 128;
  const int lane = t & 63;
  const int wave = t >> 6;
  const int wm = wave >> 1;
  const int wn = wave & 1;
  const int fr = lane & 15;
  const int fg = lane >> 4;

  f32x4 acc[4][4];
#pragma unroll
  for (int i = 0; i < 4; ++i)
#pragma unroll
    for (int j = 0; j < 4; ++j) acc[i][j] = (f32x4)(0.f);

  for (int srcp = 0; srcp < 2; ++srcp) {
    const unsigned short* __restrict__ Ah = srcp ? A2h : A1h;
    const unsigned short* __restrict__ Al = srcp ? A2l : A1l;
    const unsigned short* __restrict__ Bh = srcp ? W2h : W1h;
    const unsigned short* __restrict__ Bl = srcp ? W2l : W1l;
    for (int ks = 0; ks < K1 / 32; ++ks) {
      const int kb = ks * 32;
      // stage A tile: 128 rows x 32 k per plane (2 uint4/thread/plane)
#pragma unroll
      for (int i = 0; i < 2; ++i) {
        int idx = t + i * 256;
        int r = idx >> 2;
        int q = idx & 3;
        uint4 vh = *(const uint4*)(Ah + (size_t)(row0 + r) * K1 + kb + q * 8);
        *(uint4*)(As_hi + r * 40 + q * 8) = vh;
        uint4 vl = *(const uint4*)(Al + (size_t)(row0 + r) * K1 + kb + q * 8);
        *(uint4*)(As_lo + r * 40 + q * 8) = vl;
      }
      // stage B tile: 128 n-rows x 32 k per plane
#pragma unroll
      for (int i = 0; i < 2; ++i) {
        int idx = t + i * 256;
        int r = idx >> 2;
        int q = idx & 3;
        uint4 vh = *(const uint4*)(Bh + (size_t)(col0 + r) * K1 + kb + q * 8);
        *(uint4*)(Bs_hi + r * 40 + q * 8) = vh;
        uint4 vl = *(const uint4*)(Bl + (size_t)(col0 + r) * K1 + kb + q * 8);
        *(uint4*)(Bs_lo + r * 40 + q * 8) = vl;
      }
      __syncthreads();

      short8 ah[4], al[4];
#pragma unroll
      for (int mi = 0; mi < 4; ++mi) {
        int r = wm * 64 + mi * 16 + fr;
        ah[mi] = *(const short8*)(As_hi + r * 40 + fg * 8);
        al[mi] = *(const short8*)(As_lo + r * 40 + fg * 8);
      }
#pragma unroll
      for (int ni = 0; ni < 4; ++ni) {
        int rn = wn * 64 + ni * 16 + fr;
        short8 bh = *(const short8*)(Bs_hi + rn * 40 + fg * 8);
        short8 bl = *(const short8*)(Bs_lo + rn * 40 + fg * 8);
#pragma unroll
        for (int mi = 0; mi < 4; ++mi) {
          acc[mi][ni] = __builtin_amdgcn_mfma_f32_16x16x32_bf16(ah[mi], bh, acc[mi][ni], 0, 0, 0);
          acc[mi][ni] = __builtin_amdgcn_mfma_f32_16x16x32_bf16(al[mi], bh, acc[mi][ni], 0, 0, 0);
          acc[mi][ni] = __builtin_amdgcn_mfma_f32_16x16x32_bf16(ah[mi], bl, acc[mi][ni], 0, 0, 0);
        }
      }
      __syncthreads();
    }
  }

  // epilogue: bias + relu + split + store both planes
#pragma unroll
  for (int ni = 0; ni < 4; ++ni) {
    int col = col0 + wn * 64 + ni * 16 + fr;
    float b = bias[col];
#pragma unroll
    for (int mi = 0; mi < 4; ++mi) {
#pragma unroll
      for (int r = 0; r < 4; ++r) {
        int row = row0 + wm * 64 + mi * 16 + fg * 4 + r;
        float v = fmaxf(acc[mi][ni][r] + b, 0.f);
        unsigned short hb, lb;
        split2(v, &hb, &lb);
        outh[(size_t)row * 256 + col] = hb;
        outl[(size_t)row * 256 + col] = lb;
      }
    }
  }
}

// ---------------- global_add_pool (batch sorted), hi+lo planes ----------------
__global__ void pool_sum2(const unsigned short* __restrict__ xh, const unsigned short* __restrict__ xl,
                          const int* __restrict__ batch, float* __restrict__ g) {
  int gr = blockIdx.x;
  int lane = threadIdx.x; // 64
  int lo = 0, hi = N_NODES;
  while (lo < hi) { int mid = (lo + hi) >> 1; if (batch[mid] < gr) lo = mid + 1; else hi = mid; }
  int s = lo;
  hi = N_NODES;
  while (lo < hi) { int mid = (lo + hi) >> 1; if (batch[mid] <= gr) lo = mid + 1; else hi = mid; }
  int e = lo;
  float a0 = 0.f, a1 = 0.f, a2 = 0.f, a3 = 0.f;
  for (int i = s; i < e; ++i) {
    uint2 vh = *(const uint2*)(xh + (size_t)i * 256 + lane * 4);
    uint2 vl = *(const uint2*)(xl + (size_t)i * 256 + lane * 4);
    a0 += __uint_as_float(vh.x << 16) + __uint_as_float(vl.x << 16);
    a1 += __uint_as_float(vh.x & 0xffff0000u) + __uint_as_float(vl.x & 0xffff0000u);
    a2 += __uint_as_float(vh.y << 16) + __uint_as_float(vl.y << 16);
    a3 += __uint_as_float(vh.y & 0xffff0000u) + __uint_as_float(vl.y & 0xffff0000u);
  }
  *(float4*)(g + (size_t)gr * 256 + lane * 4) = make_float4(a0, a1, a2, a3);
}

// ---------------- small MLP layers (fp32) ----------------
template<int K, bool RELU>
__global__ void small_linear(const float* __restrict__ A, const float* __restrict__ W,
                             const float* __restrict__ bias, float* __restrict__ out, int N) {
  int g = blockIdx.x;
  int n = blockIdx.y * 64 + threadIdx.x;
  const float* a = A + (size_t)g * K;
  float acc = bias[n];
  for (int k = 0; k < K; ++k) acc = fmaf(a[k], W[(size_t)k * N + n], acc);
  if (RELU) acc = fmaxf(acc, 0.f);
  out[(size_t)g * N + n] = acc;
}

__global__ void out_layer(const float* __restrict__ h, const float* __restrict__ w,
                          const float* __restrict__ b, float* __restrict__ out) {
  int g = blockIdx.x;
  int t = threadIdx.x; // 64
  float acc = 0.f;
  for (int k = t; k < HID; k += 64) acc = fmaf(h[(size_t)g * HID + k], w[k], acc);
  for (int off = 32; off > 0; off >>= 1) acc += __shfl_down(acc, off);
  if (t == 0) out[g] = acc + b[0];
}

extern "C" void kernel_launch(void* const* d_in, const int* in_sizes, int n_in,
                              void* d_out, int out_size, void* d_ws, size_t ws_size,
                              hipStream_t stream) {
  const int* x_idx = (const int*)d_in[0];
  const int* edge_index = (const int*)d_in[1];
  const int* batch = (const int*)d_in[2];
  const float* embed = (const float*)d_in[3];
  const float* w_rel0 = (const float*)d_in[4];
  const float* b_rel0 = (const float*)d_in[5];
  const float* w_root0 = (const float*)d_in[6];
  const float* w_rel = (const float*)d_in[7];
  const float* b_rel = (const float*)d_in[8];
  const float* w_root = (const float*)d_in[9];
  const float* w_lin0 = (const float*)d_in[10];
  const float* b_lin0 = (const float*)d_in[11];
  const float* w_lin = (const float*)d_in[12];
  const float* b_lin = (const float*)d_in[13];
  const float* w_out = (const float*)d_in[14];
  const float* b_out = (const float*)d_in[15];
  float* out = (float*)d_out;

  const int* src = edge_index;
  const int* dst = edge_index + N_EDGES;

  char* ws = (char*)d_ws;
  size_t off = 0;
  auto alloc = [&](size_t bytes) -> void* {
    void* p = ws + off;
    off = (off + bytes + 255) & ~(size_t)255;
    return p;
  };
  int* deg     = (int*)alloc((size_t)N_NODES * 4);
  int* cursor  = (int*)alloc((size_t)N_NODES * 4);
  int* offs    = (int*)alloc((size_t)(N_NODES + 1) * 4);
  int* partial = (int*)alloc((size_t)SCAN_BLOCKS * 4);
  int* csr     = (int*)alloc((size_t)N_EDGES * 4);
  unsigned short* x0h = (unsigned short*)alloc((size_t)MP * EMB * 2);
  unsigned short* x0l = (unsigned short*)alloc((size_t)MP * EMB * 2);
  unsigned short* aggh = (unsigned short*)alloc((size_t)MP * CC * 2);
  unsigned short* aggl = (unsigned short*)alloc((size_t)MP * CC * 2);
  unsigned short* xAh = (unsigned short*)alloc((size_t)MP * CC * 2);
  unsigned short* xAl = (unsigned short*)alloc((size_t)MP * CC * 2);
  unsigned short* xBh = (unsigned short*)alloc((size_t)MP * CC * 2);
  unsigned short* xBl = (unsigned short*)alloc((size_t)MP * CC * 2);
  unsigned short* w0rel_h  = (unsigned short*)alloc((size_t)CC * EMB * 2);
  unsigned short* w0rel_l  = (unsigned short*)alloc((size_t)CC * EMB * 2);
  unsigned short* w0root_h = (unsigned short*)alloc((size_t)CC * EMB * 2);
  unsigned short* w0root_l = (unsigned short*)alloc((size_t)CC * EMB * 2);
  unsigned short* wrel_h  = (unsigned short*)alloc((size_t)L_CONV * CC * CC * 2);
  unsigned short* wrel_l  = (unsigned short*)alloc((size_t)L_CONV * CC * CC * 2);
  unsigned short* wroot_h = (unsigned short*)alloc((size_t)L_CONV * CC * CC * 2);
  unsigned short* wroot_l = (unsigned short*)alloc((size_t)L_CONV * CC * CC * 2);
  float* gb = (float*)alloc((size_t)N_GRAPHS * CC * 4);
  float* h1 = (float*)alloc((size_t)N_GRAPHS * HID * 4);
  float* h2 = (float*)alloc((size_t)N_GRAPHS * HID * 4);

  // CSR build (parallel scan)
  zero_ints<<<(N_NODES + 255) / 256, 256, 0, stream>>>(deg, N_NODES);
  count_deg<<<N_EDGES / 256, 256, 0, stream>>>(dst, deg);
  scan_partial<<<SCAN_BLOCKS, 256, 0, stream>>>(deg, partial);
  scan_top<<<1, 256, 0, stream>>>(partial);
  scan_final<<<SCAN_BLOCKS, 256, 0, stream>>>(deg, partial, offs, cursor);
  scatter_edges<<<N_EDGES / 256, 256, 0, stream>>>(src, dst, cursor, csr);

  // weight prep
  transpose_split<<<(EMB * CC + 255) / 256, 256, 0, stream>>>(w_rel0, w0rel_h, w0rel_l, EMB, CC);
  transpose_split<<<(EMB * CC + 255) / 256, 256, 0, stream>>>(w_root0, w0root_h, w0root_l, EMB, CC);
  transpose_split_all<<<(L_CONV * CC * CC + 255) / 256, 256, 0, stream>>>(w_rel, wrel_h, wrel_l);
  transpose_split_all<<<(L_CONV * CC * CC + 255) / 256, 256, 0, stream>>>(w_root, wroot_h, wroot_l);

  // x0 = embed[x_idx] -> hi/lo planes
  embed_gather_split<<<(N_NODES * EMB) / 256, 256, 0, stream>>>(x_idx, embed, x0h, x0l);

  dim3 gemm_grid(MP / 128, CC / 128);

  // layer 0: EMB -> CC
  aggregate_bf64<<<(N_NODES + 3) / 4, 256, 0, stream>>>(x0h, offs, csr, aggh, aggl);
  gemm_conv<EMB><<<gemm_grid, 256, 0, stream>>>(aggh, aggl, x0h, x0l,
      w0rel_h, w0rel_l, w0root_h, w0root_l, b_rel0, xAh, xAl);

  // layers 1..5
  unsigned short *curh = xAh, *curl = xAl, *nxth = xBh, *nxtl = xBl;
  for (int l = 0; l < L_CONV; ++l) {
    size_t o = (size_t)l * CC * CC;
    aggregate_bf<<<(N_NODES + 3) / 4, 256, 0, stream>>>(curh, offs, csr, aggh, aggl);
    gemm_conv<CC><<<gemm_grid, 256, 0, stream>>>(aggh, aggl, curh, curl,
        wrel_h + o, wrel_l + o, wroot_h + o, wroot_l + o, b_rel + (size_t)l * CC, nxth, nxtl);
    unsigned short* t0 = curh; curh = nxth; nxth = t0;
    unsigned short* t1 = curl; curl = nxtl; nxtl = t1;
  }

  // pooling + MLP
  pool_sum2<<<N_GRAPHS, 64, 0, stream>>>(curh, curl, batch, gb);
  small_linear<CC, true><<<dim3(N_GRAPHS, HID / 64), 64, 0, stream>>>(gb, w_lin0, b_lin0, h1, HID);
  small_linear<HID, true><<<dim3(N_GRAPHS, HID / 64), 64, 0, stream>>>(h1, w_lin, b_lin, h2, HID);
  small_linear<HID, true><<<dim3(N_GRAPHS, HID / 64), 64, 0, stream>>>(h2, w_lin + HID * HID, b_lin + HID, h1, HID);
  out_layer<<<N_GRAPHS, 64, 0, stream>>>(h1, w_out, b_out, out);
}

// Round 4
// 938.212 us; speedup vs baseline: 1.8592x; 1.1000x over previous
//
#include <hip/hip_runtime.h>
#include <hip/hip_bf16.h>

#define N_FP 10000
#define EMB 64
#define L_CONV 5
#define CC 256
#define HID 512
#define N_NODES 40000
#define N_EDGES 640000
#define N_GRAPHS 128
#define MP 40064           // N_NODES padded to multiple of 128
#define SCAN_BLOCKS 157    // ceil(40000/256)
#define POOL_CHUNK 128
#define POOL_BLOCKS 313    // ceil(40000/128)

typedef __attribute__((ext_vector_type(8))) short short8;
typedef __attribute__((ext_vector_type(4))) float f32x4;

// ---------- bf16 split helpers ----------
__device__ inline unsigned short f2bf(float x) {
  __hip_bfloat16 b = __float2bfloat16(x);
  return *reinterpret_cast<unsigned short*>(&b);
}
__device__ inline float bf2f(unsigned short u) {
  return __uint_as_float((unsigned int)u << 16);
}
__device__ inline void split2(float x, unsigned short* h, unsigned short* l) {
  unsigned short hb = f2bf(x);
  *h = hb;
  *l = f2bf(x - bf2f(hb));
}

// ---------------- CSR build ----------------
__global__ void zero_ints(int* __restrict__ p, int n) {
  int i = blockIdx.x * blockDim.x + threadIdx.x;
  if (i < n) p[i] = 0;
}

__global__ void count_deg(const int* __restrict__ dst, int* __restrict__ deg) {
  int e = blockIdx.x * blockDim.x + threadIdx.x;
  if (e < N_EDGES) atomicAdd(&deg[dst[e]], 1);
}

// parallel scan: per-block reduce -> tiny top scan -> per-block scan
__global__ void scan_partial(const int* __restrict__ deg, int* __restrict__ partial) {
  __shared__ int sm[256];
  int t = threadIdx.x;
  int idx = blockIdx.x * 256 + t;
  sm[t] = (idx < N_NODES) ? deg[idx] : 0;
  __syncthreads();
  for (int off = 128; off > 0; off >>= 1) {
    if (t < off) sm[t] += sm[t + off];
    __syncthreads();
  }
  if (t == 0) partial[blockIdx.x] = sm[0];
}

__global__ void scan_top(int* __restrict__ partial) {
  __shared__ int sm[256];
  int t = threadIdx.x;
  int own = (t < SCAN_BLOCKS) ? partial[t] : 0;
  sm[t] = own;
  __syncthreads();
  for (int off = 1; off < 256; off <<= 1) {
    int v = (t >= off) ? sm[t - off] : 0;
    __syncthreads();
    sm[t] += v;
    __syncthreads();
  }
  if (t < SCAN_BLOCKS) partial[t] = sm[t] - own;  // exclusive
}

__global__ void scan_final(const int* __restrict__ deg, const int* __restrict__ partial,
                           int* __restrict__ offs, int* __restrict__ cursor) {
  __shared__ int sm[256];
  int t = threadIdx.x;
  int idx = blockIdx.x * 256 + t;
  int own = (idx < N_NODES) ? deg[idx] : 0;
  sm[t] = own;
  __syncthreads();
  for (int off = 1; off < 256; off <<= 1) {
    int v = (t >= off) ? sm[t - off] : 0;
    __syncthreads();
    sm[t] += v;
    __syncthreads();
  }
  int excl = sm[t] - own + partial[blockIdx.x];
  if (idx < N_NODES) { offs[idx] = excl; cursor[idx] = excl; }
  if (idx == N_NODES - 1) offs[N_NODES] = excl + own;
}

__global__ void scatter_edges(const int* __restrict__ src, const int* __restrict__ dst,
                              int* __restrict__ cursor, int* __restrict__ csr) {
  int e = blockIdx.x * blockDim.x + threadIdx.x;
  if (e < N_EDGES) {
    int d = dst[e];
    int slot = atomicAdd(&cursor[d], 1);
    csr[slot] = src[e];
  }
}

// ---------------- weight transpose + split ----------------
__global__ void transpose_split(const float* __restrict__ W, unsigned short* __restrict__ hi,
                                unsigned short* __restrict__ lo, int K, int N) {
  int i = blockIdx.x * 256 + threadIdx.x;
  if (i >= K * N) return;
  int k = i / N, n = i % N;
  unsigned short hb, lb;
  split2(W[i], &hb, &lb);
  hi[(size_t)n * K + k] = hb;
  lo[(size_t)n * K + k] = lb;
}

__global__ void transpose_split_all(const float* __restrict__ W, unsigned short* __restrict__ hi,
                                    unsigned short* __restrict__ lo) {
  int i = blockIdx.x * 256 + threadIdx.x;
  if (i >= L_CONV * CC * CC) return;
  int l = i >> 16;
  int rem = i & 65535;
  int k = rem >> 8, n = rem & 255;
  unsigned short hb, lb;
  split2(W[i], &hb, &lb);
  size_t o = ((size_t)l << 16) + n * CC + k;
  hi[o] = hb;
  lo[o] = lb;
}

// ---------------- embedding gather (hi/lo planes) ----------------
__global__ void embed_gather_split(const int* __restrict__ x_idx, const float* __restrict__ emb,
                                   unsigned short* __restrict__ xh, unsigned short* __restrict__ xl) {
  int i = blockIdx.x * 256 + threadIdx.x;
  int n = i >> 6;
  int c = i & 63;
  unsigned short hb, lb;
  split2(emb[(size_t)x_idx[n] * EMB + c], &hb, &lb);
  xh[i] = hb;
  xl[i] = lb;
}

// ---------------- aggregation: wave per node, bf16-hi gather ----------------
__global__ void aggregate_bf64(const unsigned short* __restrict__ xh, const int* __restrict__ offs,
                               const int* __restrict__ csr, unsigned short* __restrict__ aggh,
                               unsigned short* __restrict__ aggl) {
  int wid = (blockIdx.x * blockDim.x + threadIdx.x) >> 6;
  int lane = threadIdx.x & 63;
  if (wid >= N_NODES) return;
  int s = offs[wid], e = offs[wid + 1];
  float a = 0.f;
  for (int j = s; j < e; ++j) a += bf2f(xh[(size_t)csr[j] * 64 + lane]);
  unsigned short hb, lb;
  split2(a, &hb, &lb);
  aggh[(size_t)wid * 64 + lane] = hb;
  aggl[(size_t)wid * 64 + lane] = lb;
}

__global__ void aggregate_bf(const unsigned short* __restrict__ xh, const int* __restrict__ offs,
                             const int* __restrict__ csr, unsigned short* __restrict__ aggh,
                             unsigned short* __restrict__ aggl) {
  int wid = (blockIdx.x * blockDim.x + threadIdx.x) >> 6;
  int lane = threadIdx.x & 63;
  if (wid >= N_NODES) return;
  int s = offs[wid], e = offs[wid + 1];
  float a0 = 0.f, a1 = 0.f, a2 = 0.f, a3 = 0.f;
  for (int j = s; j < e; ++j) {
    int sv = csr[j];
    uint2 v = *(const uint2*)(xh + (size_t)sv * 256 + lane * 4);
    a0 += __uint_as_float(v.x << 16);
    a1 += __uint_as_float(v.x & 0xffff0000u);
    a2 += __uint_as_float(v.y << 16);
    a3 += __uint_as_float(v.y & 0xffff0000u);
  }
  ushort4 oh, ol;
  split2(a0, &oh.x, &ol.x);
  split2(a1, &oh.y, &ol.y);
  split2(a2, &oh.z, &ol.z);
  split2(a3, &oh.w, &ol.w);
  *(ushort4*)(aggh + (size_t)wid * 256 + lane * 4) = oh;
  *(ushort4*)(aggl + (size_t)wid * 256 + lane * 4) = ol;
}

// ---------------- MFMA split-bf16 dual GEMM (hi/lo planes) ----------------
template<int K1>
__global__ __launch_bounds__(256)
void gemm_conv(const unsigned short* __restrict__ A1h, const unsigned short* __restrict__ A1l,
               const unsigned short* __restrict__ A2h, const unsigned short* __restrict__ A2l,
               const unsigned short* __restrict__ W1h, const unsigned short* __restrict__ W1l,
               const unsigned short* __restrict__ W2h, const unsigned short* __restrict__ W2l,
               const float* __restrict__ bias, unsigned short* __restrict__ outh,
               unsigned short* __restrict__ outl) {
  __shared__ __align__(16) unsigned short As_hi[128 * 40];
  __shared__ __align__(16) unsigned short As_lo[128 * 40];
  __shared__ __align__(16) unsigned short Bs_hi[128 * 40];
  __shared__ __align__(16) unsigned short Bs_lo[128 * 40];

  const int t = threadIdx.x;
  const int row0 = blockIdx.x * 128;
  const int col0 = blockIdx.y * 128;
  const int lane = t & 63;
  const int wave = t >> 6;
  const int wm = wave >> 1;
  const int wn = wave & 1;
  const int fr = lane & 15;
  const int fg = lane >> 4;

  f32x4 acc[4][4];
#pragma unroll
  for (int i = 0; i < 4; ++i)
#pragma unroll
    for (int j = 0; j < 4; ++j) acc[i][j] = (f32x4)(0.f);

  for (int srcp = 0; srcp < 2; ++srcp) {
    const unsigned short* __restrict__ Ah = srcp ? A2h : A1h;
    const unsigned short* __restrict__ Al = srcp ? A2l : A1l;
    const unsigned short* __restrict__ Bh = srcp ? W2h : W1h;
    const unsigned short* __restrict__ Bl = srcp ? W2l : W1l;
    for (int ks = 0; ks < K1 / 32; ++ks) {
      const int kb = ks * 32;
#pragma unroll
      for (int i = 0; i < 2; ++i) {
        int idx = t + i * 256;
        int r = idx >> 2;
        int q = idx & 3;
        uint4 vh = *(const uint4*)(Ah + (size_t)(row0 + r) * K1 + kb + q * 8);
        *(uint4*)(As_hi + r * 40 + q * 8) = vh;
        uint4 vl = *(const uint4*)(Al + (size_t)(row0 + r) * K1 + kb + q * 8);
        *(uint4*)(As_lo + r * 40 + q * 8) = vl;
      }
#pragma unroll
      for (int i = 0; i < 2; ++i) {
        int idx = t + i * 256;
        int r = idx >> 2;
        int q = idx & 3;
        uint4 vh = *(const uint4*)(Bh + (size_t)(col0 + r) * K1 + kb + q * 8);
        *(uint4*)(Bs_hi + r * 40 + q * 8) = vh;
        uint4 vl = *(const uint4*)(Bl + (size_t)(col0 + r) * K1 + kb + q * 8);
        *(uint4*)(Bs_lo + r * 40 + q * 8) = vl;
      }
      __syncthreads();

      short8 ah[4], al[4];
#pragma unroll
      for (int mi = 0; mi < 4; ++mi) {
        int r = wm * 64 + mi * 16 + fr;
        ah[mi] = *(const short8*)(As_hi + r * 40 + fg * 8);
        al[mi] = *(const short8*)(As_lo + r * 40 + fg * 8);
      }
#pragma unroll
      for (int ni = 0; ni < 4; ++ni) {
        int rn = wn * 64 + ni * 16 + fr;
        short8 bh = *(const short8*)(Bs_hi + rn * 40 + fg * 8);
        short8 bl = *(const short8*)(Bs_lo + rn * 40 + fg * 8);
#pragma unroll
        for (int mi = 0; mi < 4; ++mi) {
          acc[mi][ni] = __builtin_amdgcn_mfma_f32_16x16x32_bf16(ah[mi], bh, acc[mi][ni], 0, 0, 0);
          acc[mi][ni] = __builtin_amdgcn_mfma_f32_16x16x32_bf16(al[mi], bh, acc[mi][ni], 0, 0, 0);
          acc[mi][ni] = __builtin_amdgcn_mfma_f32_16x16x32_bf16(ah[mi], bl, acc[mi][ni], 0, 0, 0);
        }
      }
      __syncthreads();
    }
  }

#pragma unroll
  for (int ni = 0; ni < 4; ++ni) {
    int col = col0 + wn * 64 + ni * 16 + fr;
    float b = bias[col];
#pragma unroll
    for (int mi = 0; mi < 4; ++mi) {
#pragma unroll
      for (int r = 0; r < 4; ++r) {
        int row = row0 + wm * 64 + mi * 16 + fg * 4 + r;
        float v = fmaxf(acc[mi][ni][r] + b, 0.f);
        unsigned short hb, lb;
        split2(v, &hb, &lb);
        outh[(size_t)row * 256 + col] = hb;
        outl[(size_t)row * 256 + col] = lb;
      }
    }
  }
}

// ---------------- global_add_pool: chunked, atomic flush at graph boundaries ----------------
__global__ void pool_sum_chunk(const unsigned short* __restrict__ xh, const unsigned short* __restrict__ xl,
                               const int* __restrict__ batch, float* __restrict__ gb) {
  int wave = threadIdx.x >> 6;
  int lane = threadIdx.x & 63;
  int c0 = blockIdx.x * POOL_CHUNK;
  int c1 = min(c0 + POOL_CHUNK, N_NODES);
  float a0 = 0.f, a1 = 0.f, a2 = 0.f, a3 = 0.f;
  int curb = -1;
  for (int i = c0 + wave; i < c1; i += 4) {
    int b = batch[i];
    if (b != curb) {
      if (curb >= 0) {
        float* g = gb + (size_t)curb * 256 + lane * 4;
        atomicAdd(g + 0, a0); atomicAdd(g + 1, a1);
        atomicAdd(g + 2, a2); atomicAdd(g + 3, a3);
      }
      curb = b;
      a0 = a1 = a2 = a3 = 0.f;
    }
    uint2 vh = *(const uint2*)(xh + (size_t)i * 256 + lane * 4);
    uint2 vl = *(const uint2*)(xl + (size_t)i * 256 + lane * 4);
    a0 += __uint_as_float(vh.x << 16) + __uint_as_float(vl.x << 16);
    a1 += __uint_as_float(vh.x & 0xffff0000u) + __uint_as_float(vl.x & 0xffff0000u);
    a2 += __uint_as_float(vh.y << 16) + __uint_as_float(vl.y << 16);
    a3 += __uint_as_float(vh.y & 0xffff0000u) + __uint_as_float(vl.y & 0xffff0000u);
  }
  if (curb >= 0) {
    float* g = gb + (size_t)curb * 256 + lane * 4;
    atomicAdd(g + 0, a0); atomicAdd(g + 1, a1);
    atomicAdd(g + 2, a2); atomicAdd(g + 3, a3);
  }
}

// ---------------- small MLP layers (fp32) ----------------
template<int K, bool RELU>
__global__ void small_linear(const float* __restrict__ A, const float* __restrict__ W,
                             const float* __restrict__ bias, float* __restrict__ out, int N) {
  int g = blockIdx.x;
  int n = blockIdx.y * 64 + threadIdx.x;
  const float* a = A + (size_t)g * K;
  float acc = bias[n];
  for (int k = 0; k < K; ++k) acc = fmaf(a[k], W[(size_t)k * N + n], acc);
  if (RELU) acc = fmaxf(acc, 0.f);
  out[(size_t)g * N + n] = acc;
}

__global__ void out_layer(const float* __restrict__ h, const float* __restrict__ w,
                          const float* __restrict__ b, float* __restrict__ out) {
  int g = blockIdx.x;
  int t = threadIdx.x; // 64
  float acc = 0.f;
  for (int k = t; k < HID; k += 64) acc = fmaf(h[(size_t)g * HID + k], w[k], acc);
  for (int off = 32; off > 0; off >>= 1) acc += __shfl_down(acc, off);
  if (t == 0) out[g] = acc + b[0];
}

extern "C" void kernel_launch(void* const* d_in, const int* in_sizes, int n_in,
                              void* d_out, int out_size, void* d_ws, size_t ws_size,
                              hipStream_t stream) {
  const int* x_idx = (const int*)d_in[0];
  const int* edge_index = (const int*)d_in[1];
  const int* batch = (const int*)d_in[2];
  const float* embed = (const float*)d_in[3];
  const float* w_rel0 = (const float*)d_in[4];
  const float* b_rel0 = (const float*)d_in[5];
  const float* w_root0 = (const float*)d_in[6];
  const float* w_rel = (const float*)d_in[7];
  const float* b_rel = (const float*)d_in[8];
  const float* w_root = (const float*)d_in[9];
  const float* w_lin0 = (const float*)d_in[10];
  const float* b_lin0 = (const float*)d_in[11];
  const float* w_lin = (const float*)d_in[12];
  const float* b_lin = (const float*)d_in[13];
  const float* w_out = (const float*)d_in[14];
  const float* b_out = (const float*)d_in[15];
  float* out = (float*)d_out;

  const int* src = edge_index;
  const int* dst = edge_index + N_EDGES;

  char* ws = (char*)d_ws;
  size_t off = 0;
  auto alloc = [&](size_t bytes) -> void* {
    void* p = ws + off;
    off = (off + bytes + 255) & ~(size_t)255;
    return p;
  };
  int* deg     = (int*)alloc((size_t)N_NODES * 4);
  int* cursor  = (int*)alloc((size_t)N_NODES * 4);
  int* offs    = (int*)alloc((size_t)(N_NODES + 1) * 4);
  int* partial = (int*)alloc((size_t)SCAN_BLOCKS * 4);
  int* csr     = (int*)alloc((size_t)N_EDGES * 4);
  unsigned short* x0h = (unsigned short*)alloc((size_t)MP * EMB * 2);
  unsigned short* x0l = (unsigned short*)alloc((size_t)MP * EMB * 2);
  unsigned short* aggh = (unsigned short*)alloc((size_t)MP * CC * 2);
  unsigned short* aggl = (unsigned short*)alloc((size_t)MP * CC * 2);
  unsigned short* xAh = (unsigned short*)alloc((size_t)MP * CC * 2);
  unsigned short* xAl = (unsigned short*)alloc((size_t)MP * CC * 2);
  unsigned short* xBh = (unsigned short*)alloc((size_t)MP * CC * 2);
  unsigned short* xBl = (unsigned short*)alloc((size_t)MP * CC * 2);
  unsigned short* w0rel_h  = (unsigned short*)alloc((size_t)CC * EMB * 2);
  unsigned short* w0rel_l  = (unsigned short*)alloc((size_t)CC * EMB * 2);
  unsigned short* w0root_h = (unsigned short*)alloc((size_t)CC * EMB * 2);
  unsigned short* w0root_l = (unsigned short*)alloc((size_t)CC * EMB * 2);
  unsigned short* wrel_h  = (unsigned short*)alloc((size_t)L_CONV * CC * CC * 2);
  unsigned short* wrel_l  = (unsigned short*)alloc((size_t)L_CONV * CC * CC * 2);
  unsigned short* wroot_h = (unsigned short*)alloc((size_t)L_CONV * CC * CC * 2);
  unsigned short* wroot_l = (unsigned short*)alloc((size_t)L_CONV * CC * CC * 2);
  float* gb = (float*)alloc((size_t)N_GRAPHS * CC * 4);
  float* h1 = (float*)alloc((size_t)N_GRAPHS * HID * 4);
  float* h2 = (float*)alloc((size_t)N_GRAPHS * HID * 4);

  // CSR build (parallel scan)
  zero_ints<<<(N_NODES + 255) / 256, 256, 0, stream>>>(deg, N_NODES);
  count_deg<<<N_EDGES / 256, 256, 0, stream>>>(dst, deg);
  scan_partial<<<SCAN_BLOCKS, 256, 0, stream>>>(deg, partial);
  scan_top<<<1, 256, 0, stream>>>(partial);
  scan_final<<<SCAN_BLOCKS, 256, 0, stream>>>(deg, partial, offs, cursor);
  scatter_edges<<<N_EDGES / 256, 256, 0, stream>>>(src, dst, cursor, csr);

  // weight prep
  transpose_split<<<(EMB * CC + 255) / 256, 256, 0, stream>>>(w_rel0, w0rel_h, w0rel_l, EMB, CC);
  transpose_split<<<(EMB * CC + 255) / 256, 256, 0, stream>>>(w_root0, w0root_h, w0root_l, EMB, CC);
  transpose_split_all<<<(L_CONV * CC * CC + 255) / 256, 256, 0, stream>>>(w_rel, wrel_h, wrel_l);
  transpose_split_all<<<(L_CONV * CC * CC + 255) / 256, 256, 0, stream>>>(w_root, wroot_h, wroot_l);

  // x0 = embed[x_idx] -> hi/lo planes
  embed_gather_split<<<(N_NODES * EMB) / 256, 256, 0, stream>>>(x_idx, embed, x0h, x0l);

  dim3 gemm_grid(MP / 128, CC / 128);

  // layer 0: EMB -> CC
  aggregate_bf64<<<(N_NODES + 3) / 4, 256, 0, stream>>>(x0h, offs, csr, aggh, aggl);
  gemm_conv<EMB><<<gemm_grid, 256, 0, stream>>>(aggh, aggl, x0h, x0l,
      w0rel_h, w0rel_l, w0root_h, w0root_l, b_rel0, xAh, xAl);

  // layers 1..5
  unsigned short *curh = xAh, *curl = xAl, *nxth = xBh, *nxtl = xBl;
  for (int l = 0; l < L_CONV; ++l) {
    size_t o = (size_t)l * CC * CC;
    aggregate_bf<<<(N_NODES + 3) / 4, 256, 0, stream>>>(curh, offs, csr, aggh, aggl);
    gemm_conv<CC><<<gemm_grid, 256, 0, stream>>>(aggh, aggl, curh, curl,
        wrel_h + o, wrel_l + o, wroot_h + o, wroot_l + o, b_rel + (size_t)l * CC, nxth, nxtl);
    unsigned short* t0 = curh; curh = nxth; nxth = t0;
    unsigned short* t1 = curl; curl = nxtl; nxtl = t1;
  }

  // pooling + MLP
  zero_ints<<<(N_GRAPHS * CC) / 256, 256, 0, stream>>>((int*)gb, N_GRAPHS * CC);
  pool_sum_chunk<<<POOL_BLOCKS, 256, 0, stream>>>(curh, curl, batch, gb);
  small_linear<CC, true><<<dim3(N_GRAPHS, HID / 64), 64, 0, stream>>>(gb, w_lin0, b_lin0, h1, HID);
  small_linear<HID, true><<<dim3(N_GRAPHS, HID / 64), 64, 0, stream>>>(h1, w_lin, b_lin, h2, HID);
  small_linear<HID, true><<<dim3(N_GRAPHS, HID / 64), 64, 0, stream>>>(h2, w_lin + HID * HID, b_lin + HID, h1, HID);
  out_layer<<<N_GRAPHS, 64, 0, stream>>>(h1, w_out, b_out, out);
}

// Round 5
// 596.056 us; speedup vs baseline: 2.9265x; 1.5740x over previous
//
#include <hip/hip_runtime.h>
#include <hip/hip_bf16.h>

#define N_FP 10000
#define EMB 64
#define L_CONV 5
#define CC 256
#define HID 512
#define N_NODES 40000
#define N_EDGES 640000
#define N_GRAPHS 128
#define MP 40064           // N_NODES padded to multiple of 128
#define SCAN_BLOCKS 157    // ceil(40000/256)
#define POOL_CHUNK 128
#define POOL_BLOCKS 313    // ceil(40000/128)
#define WSCALE 0.25f       // per-conv-layer weight scale (relu-homogeneous)
#define UNSCALE 4096.0f    // 4^6, exact power of two

typedef __attribute__((ext_vector_type(8))) _Float16 half8;
typedef __attribute__((ext_vector_type(4))) float f32x4;

// ---------- f16 helpers ----------
__device__ inline float h2f(unsigned int bits16) {
  return (float)__builtin_bit_cast(_Float16, (unsigned short)bits16);
}
__device__ inline unsigned short f2h(float x) {
  return __builtin_bit_cast(unsigned short, (_Float16)x);
}

// ---------------- CSR build ----------------
__global__ void zero_ints(int* __restrict__ p, int n) {
  int i = blockIdx.x * blockDim.x + threadIdx.x;
  if (i < n) p[i] = 0;
}

__global__ void count_deg(const int* __restrict__ dst, int* __restrict__ deg) {
  int e = blockIdx.x * blockDim.x + threadIdx.x;
  if (e < N_EDGES) atomicAdd(&deg[dst[e]], 1);
}

__global__ void scan_partial(const int* __restrict__ deg, int* __restrict__ partial) {
  __shared__ int sm[256];
  int t = threadIdx.x;
  int idx = blockIdx.x * 256 + t;
  sm[t] = (idx < N_NODES) ? deg[idx] : 0;
  __syncthreads();
  for (int off = 128; off > 0; off >>= 1) {
    if (t < off) sm[t] += sm[t + off];
    __syncthreads();
  }
  if (t == 0) partial[blockIdx.x] = sm[0];
}

__global__ void scan_top(int* __restrict__ partial) {
  __shared__ int sm[256];
  int t = threadIdx.x;
  int own = (t < SCAN_BLOCKS) ? partial[t] : 0;
  sm[t] = own;
  __syncthreads();
  for (int off = 1; off < 256; off <<= 1) {
    int v = (t >= off) ? sm[t - off] : 0;
    __syncthreads();
    sm[t] += v;
    __syncthreads();
  }
  if (t < SCAN_BLOCKS) partial[t] = sm[t] - own;  // exclusive
}

__global__ void scan_final(const int* __restrict__ deg, const int* __restrict__ partial,
                           int* __restrict__ offs, int* __restrict__ cursor) {
  __shared__ int sm[256];
  int t = threadIdx.x;
  int idx = blockIdx.x * 256 + t;
  int own = (idx < N_NODES) ? deg[idx] : 0;
  sm[t] = own;
  __syncthreads();
  for (int off = 1; off < 256; off <<= 1) {
    int v = (t >= off) ? sm[t - off] : 0;
    __syncthreads();
    sm[t] += v;
    __syncthreads();
  }
  int excl = sm[t] - own + partial[blockIdx.x];
  if (idx < N_NODES) { offs[idx] = excl; cursor[idx] = excl; }
  if (idx == N_NODES - 1) offs[N_NODES] = excl + own;
}

__global__ void scatter_edges(const int* __restrict__ src, const int* __restrict__ dst,
                              int* __restrict__ cursor, int* __restrict__ csr) {
  int e = blockIdx.x * blockDim.x + threadIdx.x;
  if (e < N_EDGES) {
    int d = dst[e];
    int slot = atomicAdd(&cursor[d], 1);
    csr[slot] = src[e];
  }
}

// ---------------- weight transpose + scale -> f16 [N][K] ----------------
__global__ void transpose_scale_f16(const float* __restrict__ W, unsigned short* __restrict__ out,
                                    int K, int N, float scale) {
  int i = blockIdx.x * 256 + threadIdx.x;
  if (i >= K * N) return;
  int k = i / N, n = i % N;
  out[(size_t)n * K + k] = f2h(W[i] * scale);
}

__global__ void transpose_scale_all_f16(const float* __restrict__ W, unsigned short* __restrict__ out,
                                        float scale) {
  int i = blockIdx.x * 256 + threadIdx.x;
  if (i >= L_CONV * CC * CC) return;
  int l = i >> 16;
  int rem = i & 65535;
  int k = rem >> 8, n = rem & 255;
  out[((size_t)l << 16) + n * CC + k] = f2h(W[i] * scale);
}

// ---------------- embedding gather -> f16 ----------------
__global__ void embed_gather_f16(const int* __restrict__ x_idx, const float* __restrict__ emb,
                                 unsigned short* __restrict__ x0) {
  int i = blockIdx.x * 256 + threadIdx.x;
  int n = i >> 6;
  int c = i & 63;
  x0[i] = f2h(emb[(size_t)x_idx[n] * EMB + c]);
}

// ---------------- aggregation (64 ch): 8 lanes/edge, 8 edges in flight ----------------
__global__ void aggregate64_f16(const unsigned short* __restrict__ xp, const int* __restrict__ offs,
                                const int* __restrict__ csr, unsigned short* __restrict__ aggp) {
  int wid = (blockIdx.x * blockDim.x + threadIdx.x) >> 6;
  int lane = threadIdx.x & 63;
  if (wid >= N_NODES) return;
  int gr = lane >> 3;     // edge slot 0..7
  int sl = lane & 7;      // 8 lanes x 8 halves = 64 ch
  int s = offs[wid], e = offs[wid + 1];
  float a0 = 0.f, a1 = 0.f, a2 = 0.f, a3 = 0.f, a4 = 0.f, a5 = 0.f, a6 = 0.f, a7 = 0.f;
  for (int j = s + gr; j < e; j += 8) {
    int sv = csr[j];
    uint4 v = *(const uint4*)(xp + (size_t)sv * 64 + sl * 8);
    a0 += h2f(v.x & 0xffff); a1 += h2f(v.x >> 16);
    a2 += h2f(v.y & 0xffff); a3 += h2f(v.y >> 16);
    a4 += h2f(v.z & 0xffff); a5 += h2f(v.z >> 16);
    a6 += h2f(v.w & 0xffff); a7 += h2f(v.w >> 16);
  }
#pragma unroll
  for (int off = 32; off >= 8; off >>= 1) {
    a0 += __shfl_down(a0, off); a1 += __shfl_down(a1, off);
    a2 += __shfl_down(a2, off); a3 += __shfl_down(a3, off);
    a4 += __shfl_down(a4, off); a5 += __shfl_down(a5, off);
    a6 += __shfl_down(a6, off); a7 += __shfl_down(a7, off);
  }
  if (lane < 8) {
    uint4 o;
    o.x = (unsigned int)f2h(a0) | ((unsigned int)f2h(a1) << 16);
    o.y = (unsigned int)f2h(a2) | ((unsigned int)f2h(a3) << 16);
    o.z = (unsigned int)f2h(a4) | ((unsigned int)f2h(a5) << 16);
    o.w = (unsigned int)f2h(a6) | ((unsigned int)f2h(a7) << 16);
    *(uint4*)(aggp + (size_t)wid * 64 + lane * 8) = o;
  }
}

// ---------------- aggregation (256 ch): 32 lanes/edge, 2 edges in flight ----------------
__global__ void aggregate256_f16(const unsigned short* __restrict__ xp, const int* __restrict__ offs,
                                 const int* __restrict__ csr, unsigned short* __restrict__ aggp) {
  int wid = (blockIdx.x * blockDim.x + threadIdx.x) >> 6;
  int lane = threadIdx.x & 63;
  if (wid >= N_NODES) return;
  int hw = lane >> 5;     // edge parity
  int sl = lane & 31;     // 32 lanes x 8 halves = 256 ch
  int s = offs[wid], e = offs[wid + 1];
  float a0 = 0.f, a1 = 0.f, a2 = 0.f, a3 = 0.f, a4 = 0.f, a5 = 0.f, a6 = 0.f, a7 = 0.f;
  for (int j = s + hw; j < e; j += 2) {
    int sv = csr[j];
    uint4 v = *(const uint4*)(xp + (size_t)sv * 256 + sl * 8);
    a0 += h2f(v.x & 0xffff); a1 += h2f(v.x >> 16);
    a2 += h2f(v.y & 0xffff); a3 += h2f(v.y >> 16);
    a4 += h2f(v.z & 0xffff); a5 += h2f(v.z >> 16);
    a6 += h2f(v.w & 0xffff); a7 += h2f(v.w >> 16);
  }
  a0 += __shfl_down(a0, 32); a1 += __shfl_down(a1, 32);
  a2 += __shfl_down(a2, 32); a3 += __shfl_down(a3, 32);
  a4 += __shfl_down(a4, 32); a5 += __shfl_down(a5, 32);
  a6 += __shfl_down(a6, 32); a7 += __shfl_down(a7, 32);
  if (lane < 32) {
    uint4 o;
    o.x = (unsigned int)f2h(a0) | ((unsigned int)f2h(a1) << 16);
    o.y = (unsigned int)f2h(a2) | ((unsigned int)f2h(a3) << 16);
    o.z = (unsigned int)f2h(a4) | ((unsigned int)f2h(a5) << 16);
    o.w = (unsigned int)f2h(a6) | ((unsigned int)f2h(a7) << 16);
    *(uint4*)(aggp + (size_t)wid * 256 + sl * 8) = o;
  }
}

// ---------------- MFMA f16 dual GEMM: out = relu(A1@W1 + A2@W2 + b*bscale) ----------------
// A f16 [MP][K1]; W f16 [256][K1] (pre-transposed+scaled). BK=64.
template<int K1>
__global__ __launch_bounds__(256)
void gemm_conv_f16(const unsigned short* __restrict__ A1, const unsigned short* __restrict__ A2,
                   const unsigned short* __restrict__ W1, const unsigned short* __restrict__ W2,
                   const float* __restrict__ bias, float bscale,
                   unsigned short* __restrict__ outp) {
  __shared__ __align__(16) unsigned short As[128 * 72];
  __shared__ __align__(16) unsigned short Bs[128 * 72];

  const int t = threadIdx.x;
  const int row0 = blockIdx.x * 128;
  const int col0 = blockIdx.y * 128;
  const int lane = t & 63;
  const int wave = t >> 6;
  const int wm = wave >> 1;
  const int wn = wave & 1;
  const int fr = lane & 15;
  const int fg = lane >> 4;

  f32x4 acc[4][4];
#pragma unroll
  for (int i = 0; i < 4; ++i)
#pragma unroll
    for (int j = 0; j < 4; ++j) acc[i][j] = (f32x4)(0.f);

  for (int srcp = 0; srcp < 2; ++srcp) {
    const unsigned short* __restrict__ A = srcp ? A2 : A1;
    const unsigned short* __restrict__ W = srcp ? W2 : W1;
    for (int ks = 0; ks < K1 / 64; ++ks) {
      const int kb = ks * 64;
      // stage A,B tiles: 128 rows x 64 k halves (4 uint4/thread each)
#pragma unroll
      for (int i = 0; i < 4; ++i) {
        int idx = t + i * 256;
        int r = idx >> 3;
        int q = idx & 7;
        *(uint4*)(As + r * 72 + q * 8) =
            *(const uint4*)(A + (size_t)(row0 + r) * K1 + kb + q * 8);
        *(uint4*)(Bs + r * 72 + q * 8) =
            *(const uint4*)(W + (size_t)(col0 + r) * K1 + kb + q * 8);
      }
      __syncthreads();

#pragma unroll
      for (int sub = 0; sub < 2; ++sub) {
        half8 ah[4];
#pragma unroll
        for (int mi = 0; mi < 4; ++mi) {
          int r = wm * 64 + mi * 16 + fr;
          ah[mi] = *(const half8*)(As + r * 72 + sub * 32 + fg * 8);
        }
#pragma unroll
        for (int ni = 0; ni < 4; ++ni) {
          int rn = wn * 64 + ni * 16 + fr;
          half8 bh = *(const half8*)(Bs + rn * 72 + sub * 32 + fg * 8);
#pragma unroll
          for (int mi = 0; mi < 4; ++mi) {
            acc[mi][ni] = __builtin_amdgcn_mfma_f32_16x16x32_f16(ah[mi], bh, acc[mi][ni], 0, 0, 0);
          }
        }
      }
      __syncthreads();
    }
  }

  // epilogue: scaled bias + relu + f16 store
#pragma unroll
  for (int ni = 0; ni < 4; ++ni) {
    int col = col0 + wn * 64 + ni * 16 + fr;
    float b = bias[col] * bscale;
#pragma unroll
    for (int mi = 0; mi < 4; ++mi) {
#pragma unroll
      for (int r = 0; r < 4; ++r) {
        int row = row0 + wm * 64 + mi * 16 + fg * 4 + r;
        float v = fmaxf(acc[mi][ni][r] + b, 0.f);
        outp[(size_t)row * 256 + col] = f2h(v);
      }
    }
  }
}

// ---------------- global_add_pool: chunked, atomic flush, unscale ----------------
__global__ void pool_chunk_f16(const unsigned short* __restrict__ xp, const int* __restrict__ batch,
                               float* __restrict__ gb) {
  int wave = threadIdx.x >> 6;
  int lane = threadIdx.x & 63;
  int c0 = blockIdx.x * POOL_CHUNK;
  int c1 = min(c0 + POOL_CHUNK, N_NODES);
  float a0 = 0.f, a1 = 0.f, a2 = 0.f, a3 = 0.f;
  int curb = -1;
  for (int i = c0 + wave; i < c1; i += 4) {
    int b = batch[i];
    if (b != curb) {
      if (curb >= 0) {
        float* g = gb + (size_t)curb * 256 + lane * 4;
        atomicAdd(g + 0, a0 * UNSCALE); atomicAdd(g + 1, a1 * UNSCALE);
        atomicAdd(g + 2, a2 * UNSCALE); atomicAdd(g + 3, a3 * UNSCALE);
      }
      curb = b;
      a0 = a1 = a2 = a3 = 0.f;
    }
    uint2 v = *(const uint2*)(xp + (size_t)i * 256 + lane * 4);
    a0 += h2f(v.x & 0xffff); a1 += h2f(v.x >> 16);
    a2 += h2f(v.y & 0xffff); a3 += h2f(v.y >> 16);
  }
  if (curb >= 0) {
    float* g = gb + (size_t)curb * 256 + lane * 4;
    atomicAdd(g + 0, a0 * UNSCALE); atomicAdd(g + 1, a1 * UNSCALE);
    atomicAdd(g + 2, a2 * UNSCALE); atomicAdd(g + 3, a3 * UNSCALE);
  }
}

// ---------------- small MLP layers (fp32) ----------------
template<int K, bool RELU>
__global__ void small_linear(const float* __restrict__ A, const float* __restrict__ W,
                             const float* __restrict__ bias, float* __restrict__ out, int N) {
  int g = blockIdx.x;
  int n = blockIdx.y * 64 + threadIdx.x;
  const float* a = A + (size_t)g * K;
  float acc = bias[n];
  for (int k = 0; k < K; ++k) acc = fmaf(a[k], W[(size_t)k * N + n], acc);
  if (RELU) acc = fmaxf(acc, 0.f);
  out[(size_t)g * N + n] = acc;
}

__global__ void out_layer(const float* __restrict__ h, const float* __restrict__ w,
                          const float* __restrict__ b, float* __restrict__ out) {
  int g = blockIdx.x;
  int t = threadIdx.x; // 64
  float acc = 0.f;
  for (int k = t; k < HID; k += 64) acc = fmaf(h[(size_t)g * HID + k], w[k], acc);
  for (int off = 32; off > 0; off >>= 1) acc += __shfl_down(acc, off);
  if (t == 0) out[g] = acc + b[0];
}

extern "C" void kernel_launch(void* const* d_in, const int* in_sizes, int n_in,
                              void* d_out, int out_size, void* d_ws, size_t ws_size,
                              hipStream_t stream) {
  const int* x_idx = (const int*)d_in[0];
  const int* edge_index = (const int*)d_in[1];
  const int* batch = (const int*)d_in[2];
  const float* embed = (const float*)d_in[3];
  const float* w_rel0 = (const float*)d_in[4];
  const float* b_rel0 = (const float*)d_in[5];
  const float* w_root0 = (const float*)d_in[6];
  const float* w_rel = (const float*)d_in[7];
  const float* b_rel = (const float*)d_in[8];
  const float* w_root = (const float*)d_in[9];
  const float* w_lin0 = (const float*)d_in[10];
  const float* b_lin0 = (const float*)d_in[11];
  const float* w_lin = (const float*)d_in[12];
  const float* b_lin = (const float*)d_in[13];
  const float* w_out = (const float*)d_in[14];
  const float* b_out = (const float*)d_in[15];
  float* out = (float*)d_out;

  const int* src = edge_index;
  const int* dst = edge_index + N_EDGES;

  char* ws = (char*)d_ws;
  size_t off = 0;
  auto alloc = [&](size_t bytes) -> void* {
    void* p = ws + off;
    off = (off + bytes + 255) & ~(size_t)255;
    return p;
  };
  int* deg     = (int*)alloc((size_t)N_NODES * 4);
  int* cursor  = (int*)alloc((size_t)N_NODES * 4);
  int* offs    = (int*)alloc((size_t)(N_NODES + 1) * 4);
  int* partial = (int*)alloc((size_t)SCAN_BLOCKS * 4);
  int* csr     = (int*)alloc((size_t)N_EDGES * 4);
  unsigned short* x0  = (unsigned short*)alloc((size_t)MP * EMB * 2);
  unsigned short* agg = (unsigned short*)alloc((size_t)MP * CC * 2);
  unsigned short* xA  = (unsigned short*)alloc((size_t)MP * CC * 2);
  unsigned short* xB  = (unsigned short*)alloc((size_t)MP * CC * 2);
  unsigned short* w0rel_t  = (unsigned short*)alloc((size_t)CC * EMB * 2);
  unsigned short* w0root_t = (unsigned short*)alloc((size_t)CC * EMB * 2);
  unsigned short* wrel_t  = (unsigned short*)alloc((size_t)L_CONV * CC * CC * 2);
  unsigned short* wroot_t = (unsigned short*)alloc((size_t)L_CONV * CC * CC * 2);
  float* gb = (float*)alloc((size_t)N_GRAPHS * CC * 4);
  float* h1 = (float*)alloc((size_t)N_GRAPHS * HID * 4);
  float* h2 = (float*)alloc((size_t)N_GRAPHS * HID * 4);

  // CSR build (parallel scan)
  zero_ints<<<(N_NODES + 255) / 256, 256, 0, stream>>>(deg, N_NODES);
  count_deg<<<N_EDGES / 256, 256, 0, stream>>>(dst, deg);
  scan_partial<<<SCAN_BLOCKS, 256, 0, stream>>>(deg, partial);
  scan_top<<<1, 256, 0, stream>>>(partial);
  scan_final<<<SCAN_BLOCKS, 256, 0, stream>>>(deg, partial, offs, cursor);
  scatter_edges<<<N_EDGES / 256, 256, 0, stream>>>(src, dst, cursor, csr);

  // weight prep: transpose + scale -> f16
  transpose_scale_f16<<<(EMB * CC + 255) / 256, 256, 0, stream>>>(w_rel0, w0rel_t, EMB, CC, WSCALE);
  transpose_scale_f16<<<(EMB * CC + 255) / 256, 256, 0, stream>>>(w_root0, w0root_t, EMB, CC, WSCALE);
  transpose_scale_all_f16<<<(L_CONV * CC * CC + 255) / 256, 256, 0, stream>>>(w_rel, wrel_t, WSCALE);
  transpose_scale_all_f16<<<(L_CONV * CC * CC + 255) / 256, 256, 0, stream>>>(w_root, wroot_t, WSCALE);

  // x0 = embed[x_idx] -> f16
  embed_gather_f16<<<(N_NODES * EMB) / 256, 256, 0, stream>>>(x_idx, embed, x0);

  dim3 gemm_grid(MP / 128, CC / 128);

  // layer 0: EMB -> CC (bias scale 4^-1)
  aggregate64_f16<<<(N_NODES + 3) / 4, 256, 0, stream>>>(x0, offs, csr, agg);
  gemm_conv_f16<EMB><<<gemm_grid, 256, 0, stream>>>(agg, x0, w0rel_t, w0root_t,
                                                    b_rel0, 0.25f, xA);

  // layers 1..5 (bias scale 4^-(l+2))
  const float bscales[L_CONV] = {0.0625f, 0.015625f, 3.90625e-3f, 9.765625e-4f, 2.44140625e-4f};
  unsigned short *cur = xA, *nxt = xB;
  for (int l = 0; l < L_CONV; ++l) {
    size_t o = (size_t)l * CC * CC;
    aggregate256_f16<<<(N_NODES + 3) / 4, 256, 0, stream>>>(cur, offs, csr, agg);
    gemm_conv_f16<CC><<<gemm_grid, 256, 0, stream>>>(agg, cur, wrel_t + o, wroot_t + o,
                                                     b_rel + (size_t)l * CC, bscales[l], nxt);
    unsigned short* tmp = cur; cur = nxt; nxt = tmp;
  }

  // pooling (unscale 4^6) + MLP
  zero_ints<<<(N_GRAPHS * CC) / 256, 256, 0, stream>>>((int*)gb, N_GRAPHS * CC);
  pool_chunk_f16<<<POOL_BLOCKS, 256, 0, stream>>>(cur, batch, gb);
  small_linear<CC, true><<<dim3(N_GRAPHS, HID / 64), 64, 0, stream>>>(gb, w_lin0, b_lin0, h1, HID);
  small_linear<HID, true><<<dim3(N_GRAPHS, HID / 64), 64, 0, stream>>>(h1, w_lin, b_lin, h2, HID);
  small_linear<HID, true><<<dim3(N_GRAPHS, HID / 64), 64, 0, stream>>>(h2, w_lin + HID * HID, b_lin + HID, h1, HID);
  out_layer<<<N_GRAPHS, 64, 0, stream>>>(h1, w_out, b_out, out);
}

// Round 6
// 545.367 us; speedup vs baseline: 3.1985x; 1.0929x over previous
//
#include <hip/hip_runtime.h>
#include <hip/hip_bf16.h>

#define N_FP 10000
#define EMB 64
#define L_CONV 5
#define CC 256
#define HID 512
#define N_NODES 40000
#define N_EDGES 640000
#define N_GRAPHS 128
#define MP 40064           // N_NODES padded to multiple of 128
#define SCAN_BLOCKS 157    // ceil(40000/256)
#define POOL_CHUNK 128
#define POOL_BLOCKS 313    // ceil(40000/128)
#define WSCALE 0.25f       // per-conv-layer weight scale (relu-homogeneous)
#define UNSCALE 4096.0f    // 4^6, exact power of two

typedef __attribute__((ext_vector_type(8))) _Float16 half8;
typedef __attribute__((ext_vector_type(4))) float f32x4;

// ---------- f16 helpers ----------
__device__ inline float h2f(unsigned int bits16) {
  return (float)__builtin_bit_cast(_Float16, (unsigned short)bits16);
}
__device__ inline unsigned short f2h(float x) {
  return __builtin_bit_cast(unsigned short, (_Float16)x);
}

// ---------------- CSR build ----------------
__global__ void zero_ints(int* __restrict__ p, int n) {
  int i = blockIdx.x * blockDim.x + threadIdx.x;
  if (i < n) p[i] = 0;
}

__global__ void count_deg(const int* __restrict__ dst, int* __restrict__ deg) {
  int e = blockIdx.x * blockDim.x + threadIdx.x;
  if (e < N_EDGES) atomicAdd(&deg[dst[e]], 1);
}

__global__ void scan_partial(const int* __restrict__ deg, int* __restrict__ partial) {
  __shared__ int sm[256];
  int t = threadIdx.x;
  int idx = blockIdx.x * 256 + t;
  sm[t] = (idx < N_NODES) ? deg[idx] : 0;
  __syncthreads();
  for (int off = 128; off > 0; off >>= 1) {
    if (t < off) sm[t] += sm[t + off];
    __syncthreads();
  }
  if (t == 0) partial[blockIdx.x] = sm[0];
}

__global__ void scan_top(int* __restrict__ partial) {
  __shared__ int sm[256];
  int t = threadIdx.x;
  int own = (t < SCAN_BLOCKS) ? partial[t] : 0;
  sm[t] = own;
  __syncthreads();
  for (int off = 1; off < 256; off <<= 1) {
    int v = (t >= off) ? sm[t - off] : 0;
    __syncthreads();
    sm[t] += v;
    __syncthreads();
  }
  if (t < SCAN_BLOCKS) partial[t] = sm[t] - own;  // exclusive
}

__global__ void scan_final(const int* __restrict__ deg, const int* __restrict__ partial,
                           int* __restrict__ offs, int* __restrict__ cursor) {
  __shared__ int sm[256];
  int t = threadIdx.x;
  int idx = blockIdx.x * 256 + t;
  int own = (idx < N_NODES) ? deg[idx] : 0;
  sm[t] = own;
  __syncthreads();
  for (int off = 1; off < 256; off <<= 1) {
    int v = (t >= off) ? sm[t - off] : 0;
    __syncthreads();
    sm[t] += v;
    __syncthreads();
  }
  int excl = sm[t] - own + partial[blockIdx.x];
  if (idx < N_NODES) { offs[idx] = excl; cursor[idx] = excl; }
  if (idx == N_NODES - 1) offs[N_NODES] = excl + own;
}

__global__ void scatter_edges(const int* __restrict__ src, const int* __restrict__ dst,
                              int* __restrict__ cursor, int* __restrict__ csr) {
  int e = blockIdx.x * blockDim.x + threadIdx.x;
  if (e < N_EDGES) {
    int d = dst[e];
    int slot = atomicAdd(&cursor[d], 1);
    csr[slot] = src[e];
  }
}

// ---------------- weight transpose + scale -> f16 [N][K] ----------------
__global__ void transpose_scale_f16(const float* __restrict__ W, unsigned short* __restrict__ out,
                                    int K, int N, float scale) {
  int i = blockIdx.x * 256 + threadIdx.x;
  if (i >= K * N) return;
  int k = i / N, n = i % N;
  out[(size_t)n * K + k] = f2h(W[i] * scale);
}

__global__ void transpose_scale_all_f16(const float* __restrict__ W, unsigned short* __restrict__ out,
                                        float scale) {
  int i = blockIdx.x * 256 + threadIdx.x;
  if (i >= L_CONV * CC * CC) return;
  int l = i >> 16;
  int rem = i & 65535;
  int k = rem >> 8, n = rem & 255;
  out[((size_t)l << 16) + n * CC + k] = f2h(W[i] * scale);
}

// ---------------- embedding gather -> f16 ----------------
__global__ void embed_gather_f16(const int* __restrict__ x_idx, const float* __restrict__ emb,
                                 unsigned short* __restrict__ x0) {
  int i = blockIdx.x * 256 + threadIdx.x;
  int n = i >> 6;
  int c = i & 63;
  x0[i] = f2h(emb[(size_t)x_idx[n] * EMB + c]);
}

// ---------------- aggregation (64 ch): 8 lanes/edge, 8 edges in flight ----------------
__global__ void aggregate64_f16(const unsigned short* __restrict__ xp, const int* __restrict__ offs,
                                const int* __restrict__ csr, unsigned short* __restrict__ aggp) {
  int wid = (blockIdx.x * blockDim.x + threadIdx.x) >> 6;
  int lane = threadIdx.x & 63;
  if (wid >= N_NODES) return;
  int gr = lane >> 3;     // edge slot 0..7
  int sl = lane & 7;      // 8 lanes x 8 halves = 64 ch
  int s = offs[wid], e = offs[wid + 1];
  float a0 = 0.f, a1 = 0.f, a2 = 0.f, a3 = 0.f, a4 = 0.f, a5 = 0.f, a6 = 0.f, a7 = 0.f;
  for (int j = s + gr; j < e; j += 8) {
    int sv = csr[j];
    uint4 v = *(const uint4*)(xp + (size_t)sv * 64 + sl * 8);
    a0 += h2f(v.x & 0xffff); a1 += h2f(v.x >> 16);
    a2 += h2f(v.y & 0xffff); a3 += h2f(v.y >> 16);
    a4 += h2f(v.z & 0xffff); a5 += h2f(v.z >> 16);
    a6 += h2f(v.w & 0xffff); a7 += h2f(v.w >> 16);
  }
#pragma unroll
  for (int off = 32; off >= 8; off >>= 1) {
    a0 += __shfl_down(a0, off); a1 += __shfl_down(a1, off);
    a2 += __shfl_down(a2, off); a3 += __shfl_down(a3, off);
    a4 += __shfl_down(a4, off); a5 += __shfl_down(a5, off);
    a6 += __shfl_down(a6, off); a7 += __shfl_down(a7, off);
  }
  if (lane < 8) {
    uint4 o;
    o.x = (unsigned int)f2h(a0) | ((unsigned int)f2h(a1) << 16);
    o.y = (unsigned int)f2h(a2) | ((unsigned int)f2h(a3) << 16);
    o.z = (unsigned int)f2h(a4) | ((unsigned int)f2h(a5) << 16);
    o.w = (unsigned int)f2h(a6) | ((unsigned int)f2h(a7) << 16);
    *(uint4*)(aggp + (size_t)wid * 64 + lane * 8) = o;
  }
}

// ---------------- aggregation (256 ch): 16 lanes/edge, 4 edges in flight ----------------
__global__ void aggregate256_f16(const unsigned short* __restrict__ xp, const int* __restrict__ offs,
                                 const int* __restrict__ csr, unsigned short* __restrict__ aggp) {
  int wid = (blockIdx.x * blockDim.x + threadIdx.x) >> 6;
  int lane = threadIdx.x & 63;
  if (wid >= N_NODES) return;
  int es = lane >> 4;     // edge slot 0..3
  int sl = lane & 15;     // 16 lanes x 2 x 8 halves = 256 ch
  int s = offs[wid], e = offs[wid + 1];
  float a[16];
#pragma unroll
  for (int i = 0; i < 16; ++i) a[i] = 0.f;
  for (int j = s + es; j < e; j += 4) {
    int sv = csr[j];
    uint4 v0 = *(const uint4*)(xp + (size_t)sv * 256 + sl * 8);
    uint4 v1 = *(const uint4*)(xp + (size_t)sv * 256 + 128 + sl * 8);
    a[0] += h2f(v0.x & 0xffff); a[1] += h2f(v0.x >> 16);
    a[2] += h2f(v0.y & 0xffff); a[3] += h2f(v0.y >> 16);
    a[4] += h2f(v0.z & 0xffff); a[5] += h2f(v0.z >> 16);
    a[6] += h2f(v0.w & 0xffff); a[7] += h2f(v0.w >> 16);
    a[8]  += h2f(v1.x & 0xffff); a[9]  += h2f(v1.x >> 16);
    a[10] += h2f(v1.y & 0xffff); a[11] += h2f(v1.y >> 16);
    a[12] += h2f(v1.z & 0xffff); a[13] += h2f(v1.z >> 16);
    a[14] += h2f(v1.w & 0xffff); a[15] += h2f(v1.w >> 16);
  }
#pragma unroll
  for (int off = 32; off >= 16; off >>= 1) {
#pragma unroll
    for (int i = 0; i < 16; ++i) a[i] += __shfl_down(a[i], off);
  }
  if (lane < 16) {
    uint4 o0, o1;
    o0.x = (unsigned int)f2h(a[0]) | ((unsigned int)f2h(a[1]) << 16);
    o0.y = (unsigned int)f2h(a[2]) | ((unsigned int)f2h(a[3]) << 16);
    o0.z = (unsigned int)f2h(a[4]) | ((unsigned int)f2h(a[5]) << 16);
    o0.w = (unsigned int)f2h(a[6]) | ((unsigned int)f2h(a[7]) << 16);
    o1.x = (unsigned int)f2h(a[8])  | ((unsigned int)f2h(a[9])  << 16);
    o1.y = (unsigned int)f2h(a[10]) | ((unsigned int)f2h(a[11]) << 16);
    o1.z = (unsigned int)f2h(a[12]) | ((unsigned int)f2h(a[13]) << 16);
    o1.w = (unsigned int)f2h(a[14]) | ((unsigned int)f2h(a[15]) << 16);
    *(uint4*)(aggp + (size_t)wid * 256 + sl * 8) = o0;
    *(uint4*)(aggp + (size_t)wid * 256 + 128 + sl * 8) = o1;
  }
}

// ---------------- MFMA f16 dual GEMM: out = relu(A1@W1 + A2@W2 + b*bscale) ----------------
template<int K1>
__global__ __launch_bounds__(256)
void gemm_conv_f16(const unsigned short* __restrict__ A1, const unsigned short* __restrict__ A2,
                   const unsigned short* __restrict__ W1, const unsigned short* __restrict__ W2,
                   const float* __restrict__ bias, float bscale,
                   unsigned short* __restrict__ outp) {
  __shared__ __align__(16) unsigned short As[128 * 72];
  __shared__ __align__(16) unsigned short Bs[128 * 72];

  const int t = threadIdx.x;
  const int row0 = blockIdx.x * 128;
  const int col0 = blockIdx.y * 128;
  const int lane = t & 63;
  const int wave = t >> 6;
  const int wm = wave >> 1;
  const int wn = wave & 1;
  const int fr = lane & 15;
  const int fg = lane >> 4;

  f32x4 acc[4][4];
#pragma unroll
  for (int i = 0; i < 4; ++i)
#pragma unroll
    for (int j = 0; j < 4; ++j) acc[i][j] = (f32x4)(0.f);

  for (int srcp = 0; srcp < 2; ++srcp) {
    const unsigned short* __restrict__ A = srcp ? A2 : A1;
    const unsigned short* __restrict__ W = srcp ? W2 : W1;
    for (int ks = 0; ks < K1 / 64; ++ks) {
      const int kb = ks * 64;
#pragma unroll
      for (int i = 0; i < 4; ++i) {
        int idx = t + i * 256;
        int r = idx >> 3;
        int q = idx & 7;
        *(uint4*)(As + r * 72 + q * 8) =
            *(const uint4*)(A + (size_t)(row0 + r) * K1 + kb + q * 8);
        *(uint4*)(Bs + r * 72 + q * 8) =
            *(const uint4*)(W + (size_t)(col0 + r) * K1 + kb + q * 8);
      }
      __syncthreads();

#pragma unroll
      for (int sub = 0; sub < 2; ++sub) {
        half8 ah[4];
#pragma unroll
        for (int mi = 0; mi < 4; ++mi) {
          int r = wm * 64 + mi * 16 + fr;
          ah[mi] = *(const half8*)(As + r * 72 + sub * 32 + fg * 8);
        }
#pragma unroll
        for (int ni = 0; ni < 4; ++ni) {
          int rn = wn * 64 + ni * 16 + fr;
          half8 bh = *(const half8*)(Bs + rn * 72 + sub * 32 + fg * 8);
#pragma unroll
          for (int mi = 0; mi < 4; ++mi) {
            acc[mi][ni] = __builtin_amdgcn_mfma_f32_16x16x32_f16(ah[mi], bh, acc[mi][ni], 0, 0, 0);
          }
        }
      }
      __syncthreads();
    }
  }

#pragma unroll
  for (int ni = 0; ni < 4; ++ni) {
    int col = col0 + wn * 64 + ni * 16 + fr;
    float b = bias[col] * bscale;
#pragma unroll
    for (int mi = 0; mi < 4; ++mi) {
#pragma unroll
      for (int r = 0; r < 4; ++r) {
        int row = row0 + wm * 64 + mi * 16 + fg * 4 + r;
        float v = fmaxf(acc[mi][ni][r] + b, 0.f);
        outp[(size_t)row * 256 + col] = f2h(v);
      }
    }
  }
}

// ---------------- global_add_pool: chunked, atomic flush, unscale ----------------
__global__ void pool_chunk_f16(const unsigned short* __restrict__ xp, const int* __restrict__ batch,
                               float* __restrict__ gb) {
  int wave = threadIdx.x >> 6;
  int lane = threadIdx.x & 63;
  int c0 = blockIdx.x * POOL_CHUNK;
  int c1 = min(c0 + POOL_CHUNK, N_NODES);
  float a0 = 0.f, a1 = 0.f, a2 = 0.f, a3 = 0.f;
  int curb = -1;
  for (int i = c0 + wave; i < c1; i += 4) {
    int b = batch[i];
    if (b != curb) {
      if (curb >= 0) {
        float* g = gb + (size_t)curb * 256 + lane * 4;
        atomicAdd(g + 0, a0 * UNSCALE); atomicAdd(g + 1, a1 * UNSCALE);
        atomicAdd(g + 2, a2 * UNSCALE); atomicAdd(g + 3, a3 * UNSCALE);
      }
      curb = b;
      a0 = a1 = a2 = a3 = 0.f;
    }
    uint2 v = *(const uint2*)(xp + (size_t)i * 256 + lane * 4);
    a0 += h2f(v.x & 0xffff); a1 += h2f(v.x >> 16);
    a2 += h2f(v.y & 0xffff); a3 += h2f(v.y >> 16);
  }
  if (curb >= 0) {
    float* g = gb + (size_t)curb * 256 + lane * 4;
    atomicAdd(g + 0, a0 * UNSCALE); atomicAdd(g + 1, a1 * UNSCALE);
    atomicAdd(g + 2, a2 * UNSCALE); atomicAdd(g + 3, a3 * UNSCALE);
  }
}

// ---------------- MLP linear: 4 graphs x 128 outputs per block, fp32 ----------------
template<int K, int N, bool RELU>
__global__ __launch_bounds__(512)
void mlp_linear(const float* __restrict__ A, const float* __restrict__ W,
                const float* __restrict__ bias, float* __restrict__ out) {
  __shared__ float a[4][K];
  const int t = threadIdx.x;
  const int g0 = blockIdx.x * 4;
  const int n0 = blockIdx.y * 128;
#pragma unroll
  for (int i = 0; i < (4 * K) / 512; ++i) {
    int idx = t + i * 512;
    a[idx / K][idx % K] = A[(size_t)g0 * K + idx];
  }
  __syncthreads();
  const int gl = t >> 7;          // graph slot 0..3
  const int n = n0 + (t & 127);
  const float* __restrict__ ar = a[gl];
  const float* __restrict__ w = W + n;
  float acc = bias[n];
#pragma unroll 8
  for (int k = 0; k < K; ++k) acc = fmaf(ar[k], w[(size_t)k * N], acc);
  if (RELU) acc = fmaxf(acc, 0.f);
  out[(size_t)(g0 + gl) * N + n] = acc;
}

__global__ void out_layer(const float* __restrict__ h, const float* __restrict__ w,
                          const float* __restrict__ b, float* __restrict__ out) {
  int g = blockIdx.x;
  int t = threadIdx.x; // 64
  float acc = 0.f;
#pragma unroll 4
  for (int k = t; k < HID; k += 64) acc = fmaf(h[(size_t)g * HID + k], w[k], acc);
  for (int off = 32; off > 0; off >>= 1) acc += __shfl_down(acc, off);
  if (t == 0) out[g] = acc + b[0];
}

extern "C" void kernel_launch(void* const* d_in, const int* in_sizes, int n_in,
                              void* d_out, int out_size, void* d_ws, size_t ws_size,
                              hipStream_t stream) {
  const int* x_idx = (const int*)d_in[0];
  const int* edge_index = (const int*)d_in[1];
  const int* batch = (const int*)d_in[2];
  const float* embed = (const float*)d_in[3];
  const float* w_rel0 = (const float*)d_in[4];
  const float* b_rel0 = (const float*)d_in[5];
  const float* w_root0 = (const float*)d_in[6];
  const float* w_rel = (const float*)d_in[7];
  const float* b_rel = (const float*)d_in[8];
  const float* w_root = (const float*)d_in[9];
  const float* w_lin0 = (const float*)d_in[10];
  const float* b_lin0 = (const float*)d_in[11];
  const float* w_lin = (const float*)d_in[12];
  const float* b_lin = (const float*)d_in[13];
  const float* w_out = (const float*)d_in[14];
  const float* b_out = (const float*)d_in[15];
  float* out = (float*)d_out;

  const int* src = edge_index;
  const int* dst = edge_index + N_EDGES;

  char* ws = (char*)d_ws;
  size_t off = 0;
  auto alloc = [&](size_t bytes) -> void* {
    void* p = ws + off;
    off = (off + bytes + 255) & ~(size_t)255;
    return p;
  };
  int* deg     = (int*)alloc((size_t)N_NODES * 4);
  int* cursor  = (int*)alloc((size_t)N_NODES * 4);
  int* offs    = (int*)alloc((size_t)(N_NODES + 1) * 4);
  int* partial = (int*)alloc((size_t)SCAN_BLOCKS * 4);
  int* csr     = (int*)alloc((size_t)N_EDGES * 4);
  unsigned short* x0  = (unsigned short*)alloc((size_t)MP * EMB * 2);
  unsigned short* agg = (unsigned short*)alloc((size_t)MP * CC * 2);
  unsigned short* xA  = (unsigned short*)alloc((size_t)MP * CC * 2);
  unsigned short* xB  = (unsigned short*)alloc((size_t)MP * CC * 2);
  unsigned short* w0rel_t  = (unsigned short*)alloc((size_t)CC * EMB * 2);
  unsigned short* w0root_t = (unsigned short*)alloc((size_t)CC * EMB * 2);
  unsigned short* wrel_t  = (unsigned short*)alloc((size_t)L_CONV * CC * CC * 2);
  unsigned short* wroot_t = (unsigned short*)alloc((size_t)L_CONV * CC * CC * 2);
  float* gb = (float*)alloc((size_t)N_GRAPHS * CC * 4);
  float* h1 = (float*)alloc((size_t)N_GRAPHS * HID * 4);
  float* h2 = (float*)alloc((size_t)N_GRAPHS * HID * 4);

  // CSR build (parallel scan)
  zero_ints<<<(N_NODES + 255) / 256, 256, 0, stream>>>(deg, N_NODES);
  count_deg<<<N_EDGES / 256, 256, 0, stream>>>(dst, deg);
  scan_partial<<<SCAN_BLOCKS, 256, 0, stream>>>(deg, partial);
  scan_top<<<1, 256, 0, stream>>>(partial);
  scan_final<<<SCAN_BLOCKS, 256, 0, stream>>>(deg, partial, offs, cursor);
  scatter_edges<<<N_EDGES / 256, 256, 0, stream>>>(src, dst, cursor, csr);

  // weight prep: transpose + scale -> f16
  transpose_scale_f16<<<(EMB * CC + 255) / 256, 256, 0, stream>>>(w_rel0, w0rel_t, EMB, CC, WSCALE);
  transpose_scale_f16<<<(EMB * CC + 255) / 256, 256, 0, stream>>>(w_root0, w0root_t, EMB, CC, WSCALE);
  transpose_scale_all_f16<<<(L_CONV * CC * CC + 255) / 256, 256, 0, stream>>>(w_rel, wrel_t, WSCALE);
  transpose_scale_all_f16<<<(L_CONV * CC * CC + 255) / 256, 256, 0, stream>>>(w_root, wroot_t, WSCALE);

  // x0 = embed[x_idx] -> f16
  embed_gather_f16<<<(N_NODES * EMB) / 256, 256, 0, stream>>>(x_idx, embed, x0);

  dim3 gemm_grid(MP / 128, CC / 128);

  // layer 0: EMB -> CC (bias scale 4^-1)
  aggregate64_f16<<<(N_NODES + 3) / 4, 256, 0, stream>>>(x0, offs, csr, agg);
  gemm_conv_f16<EMB><<<gemm_grid, 256, 0, stream>>>(agg, x0, w0rel_t, w0root_t,
                                                    b_rel0, 0.25f, xA);

  // layers 1..5 (bias scale 4^-(l+2))
  const float bscales[L_CONV] = {0.0625f, 0.015625f, 3.90625e-3f, 9.765625e-4f, 2.44140625e-4f};
  unsigned short *cur = xA, *nxt = xB;
  for (int l = 0; l < L_CONV; ++l) {
    size_t o = (size_t)l * CC * CC;
    aggregate256_f16<<<(N_NODES + 3) / 4, 256, 0, stream>>>(cur, offs, csr, agg);
    gemm_conv_f16<CC><<<gemm_grid, 256, 0, stream>>>(agg, cur, wrel_t + o, wroot_t + o,
                                                     b_rel + (size_t)l * CC, bscales[l], nxt);
    unsigned short* tmp = cur; cur = nxt; nxt = tmp;
  }

  // pooling (unscale 4^6) + MLP
  zero_ints<<<(N_GRAPHS * CC) / 256, 256, 0, stream>>>((int*)gb, N_GRAPHS * CC);
  pool_chunk_f16<<<POOL_BLOCKS, 256, 0, stream>>>(cur, batch, gb);
  mlp_linear<CC, HID, true><<<dim3(N_GRAPHS / 4, HID / 128), 512, 0, stream>>>(gb, w_lin0, b_lin0, h1);
  mlp_linear<HID, HID, true><<<dim3(N_GRAPHS / 4, HID / 128), 512, 0, stream>>>(h1, w_lin, b_lin, h2);
  mlp_linear<HID, HID, true><<<dim3(N_GRAPHS / 4, HID / 128), 512, 0, stream>>>(h2, w_lin + HID * HID, b_lin + HID, h1);
  out_layer<<<N_GRAPHS, 64, 0, stream>>>(h1, w_out, b_out, out);
}